// Round 7
// baseline (271.612 us; speedup 1.0000x reference)
//
#include <hip/hip_runtime.h>
#include <hip/hip_bf16.h>

#define EPS 1e-5f
#define NSf 65536.0f

typedef unsigned short u16;
typedef __attribute__((ext_vector_type(8))) unsigned short u16x8;
typedef __attribute__((ext_vector_type(4))) unsigned short u16x4;
typedef __attribute__((ext_vector_type(8))) short bf16x8;
typedef __attribute__((ext_vector_type(4))) float f32x4;

// ---------------- workspace layout (float offsets) ----------------
#define WS_Y2T   0                         // 8,388,608 bf16 (y2 pre-BN)
#define WS_W3BF  4194304                   // 131072 bf16
#define WS_W2BF  4259840                   // 8192 bf16
#define WS_S2P   4263936                   // 256 blocks * 256 f32 (sum128, sq128)
#define WS_SP    4329472                   // 64 * 12 src-moment partials
#define WS_SC2   4330240                   // 256
#define WS_SUMP  4330496                   // 16*8*1024 conv3 sum partials
#define WS_SQP   4461568                   // 16*8*1024 sq partials
#define WS_MAXP  4592640                   // 16*8*1024 max partials
#define WS_POOL  4723712                   // 8192
#define WS_FC1   4731904                   // 4096
#define WS_FC2   4736000                   // 2048
#define WS_DIST  4738048                   // 96 + counter  <- cleared in k_prep
#define WS_CNT   4738144                   // 1
#define WS_END   4738148

__device__ __forceinline__ u16 f2b(float f) {
  unsigned u = __float_as_uint(f);
  u += 0x7FFFu + ((u >> 16) & 1);
  return (u16)(u >> 16);
}
__device__ __forceinline__ float b2f(u16 h) { return __uint_as_float(((unsigned)h) << 16); }

__device__ __forceinline__ void gl16(const void* g, void* l) {
  __builtin_amdgcn_global_load_lds((const __attribute__((address_space(1))) unsigned*)g,
                                   (__attribute__((address_space(3))) unsigned*)l, 16, 0, 0);
}

// ---------------- K0: prep = wcast (544 blocks) + src moments (64) + clears --
__global__ void k_prep(const float* __restrict__ w3, const float* __restrict__ w2,
                       const float* __restrict__ src, u16* __restrict__ w3bf,
                       u16* __restrict__ w2bf, float* __restrict__ SP,
                       float* __restrict__ DIST) {
  int bid = blockIdx.x, t = threadIdx.x;
  if (bid < 544) {
    int id = bid * 256 + t;
    if (id < 131072) w3bf[id] = f2b(w3[id]);
    else w2bf[id - 131072] = f2b(w2[id - 131072]);
    return;
  }
  int sb = bid - 544;  // 0..63
  if (sb == 0 && t < 100) DIST[t] = 0.f;  // DIST[96] + CNT
  float p[9] = {0, 0, 0, 0, 0, 0, 0, 0, 0};
  for (int it = 0; it < 4; ++it) {
    int id = sb * 1024 + it * 256 + t;
    int b = id >> 13, n = id & 8191;
    float s0 = src[(b * 3 + 0) * 8192 + n];
    float s1 = src[(b * 3 + 1) * 8192 + n];
    float s2 = src[(b * 3 + 2) * 8192 + n];
    p[0] += s0; p[1] += s1; p[2] += s2;
    p[3] = fmaf(s0, s0, p[3]); p[4] = fmaf(s0, s1, p[4]); p[5] = fmaf(s0, s2, p[5]);
    p[6] = fmaf(s1, s1, p[6]); p[7] = fmaf(s1, s2, p[7]); p[8] = fmaf(s2, s2, p[8]);
  }
#pragma unroll
  for (int i = 0; i < 9; ++i)
    for (int off = 32; off; off >>= 1) p[i] += __shfl_xor(p[i], off);
  __shared__ float red[4][9];
  int wv = t >> 6;
  if ((t & 63) == 0) {
#pragma unroll
    for (int i = 0; i < 9; ++i) red[wv][i] = p[i];
  }
  __syncthreads();
  if (t < 9) SP[sb * 12 + t] = red[0][t] + red[1][t] + red[2][t] + red[3][t];
}

// ---- K1: conv2 MFMA (fin1 inlined) -> y2 pre-BN bf16 + per-block BN2 partials
__global__ __launch_bounds__(256) void k_conv2(
    const float* __restrict__ src, const float* __restrict__ SP,
    const float* __restrict__ w1, const float* __restrict__ b1,
    const float* __restrict__ g1, const float* __restrict__ be1,
    const u16* __restrict__ w2bf, u16* __restrict__ y2t, float* __restrict__ S2P) {
  __shared__ char WT[16384];  // W2 [128o][64c] bf16 swizzled
  __shared__ char XT[32768];  // x1 [256p][64c] bf16 swizzled
  __shared__ float Msh[9];
  __shared__ float effL[256];
  int t = threadIdx.x, bid = blockIdx.x;
  int lane = t & 63, lr = lane & 15, lk = lane >> 4;
  int w = __builtin_amdgcn_readfirstlane(t >> 6);
#pragma unroll
  for (int i = 0; i < 4; ++i) {
    int s = i * 4096 + t * 16;
    int o = s >> 7, cb = s & 127;
    gl16((const char*)w2bf + ((o << 7) | (cb ^ ((o & 7) << 4))), WT + s);
  }
  int P = bid * 256 + t, b = P >> 13, n = P & 8191;
  float s0 = src[(b * 3 + 0) * 8192 + n];
  float s1 = src[(b * 3 + 1) * 8192 + n];
  float s2 = src[(b * 3 + 2) * 8192 + n];
  // fin1 inline: reduce src moments, compute effective conv1 weights
  if (t < 9) {
    float s = 0.f;
    for (int bb = 0; bb < 64; ++bb) s += SP[bb * 12 + t];
    Msh[t] = s;
  }
  __syncthreads();
  if (t < 64) {
    int c = t;
    float m0 = Msh[0], m1 = Msh[1], m2 = Msh[2];
    float ss00 = Msh[3], ss01 = Msh[4], ss02 = Msh[5], ss11 = Msh[6], ss12 = Msh[7],
          ss22 = Msh[8];
    float a0 = w1[c * 3], a1 = w1[c * 3 + 1], a2 = w1[c * 3 + 2], bb = b1[c];
    float dotS = a0 * m0 + a1 * m1 + a2 * m2;
    float sumY = dotS + NSf * bb;
    float sumY2 = a0 * a0 * ss00 + a1 * a1 * ss11 + a2 * a2 * ss22
                + 2.f * (a0 * a1 * ss01 + a0 * a2 * ss02 + a1 * a2 * ss12)
                + 2.f * bb * dotS + NSf * bb * bb;
    float m = sumY / NSf;
    float v = sumY2 / NSf - m * m;
    float sc = g1[c] * rsqrtf(v + EPS);
    float sh = be1[c] - m * sc;
    effL[c * 3 + 0] = sc * a0;
    effL[c * 3 + 1] = sc * a1;
    effL[c * 3 + 2] = sc * a2;
    effL[192 + c] = sc * bb + sh;
  }
  __syncthreads();
#pragma unroll
  for (int i = 0; i < 8; ++i) {
    u16x8 pk;
#pragma unroll
    for (int e = 0; e < 8; ++e) {
      int c = i * 8 + e;
      pk[e] = f2b(fmaxf(fmaf(effL[c * 3], s0, fmaf(effL[c * 3 + 1], s1,
                        fmaf(effL[c * 3 + 2], s2, effL[192 + c]))), 0.f));
    }
    *(u16x8*)(XT + ((t << 7) | ((i * 16) ^ ((t & 7) << 4)))) = pk;
  }
  __syncthreads();
  int o0w = (w & 1) * 64, p0w = (w >> 1) * 128;
  f32x4 acc[4][8];
#pragma unroll
  for (int i = 0; i < 4; ++i)
#pragma unroll
    for (int j = 0; j < 8; ++j) acc[i][j] = (f32x4){0.f, 0.f, 0.f, 0.f};
#pragma unroll
  for (int kk = 0; kk < 2; ++kk) {
    bf16x8 a[4], bb[8];
#pragma unroll
    for (int i = 0; i < 4; ++i) {
      int row = o0w + i * 16 + lr;
      a[i] = *(const bf16x8*)(WT + ((row << 7) | ((kk * 64 + lk * 16) ^ ((row & 7) << 4))));
    }
#pragma unroll
    for (int j = 0; j < 8; ++j) {
      int prow = p0w + j * 16 + lr;
      bb[j] = *(const bf16x8*)(XT + ((prow << 7) | ((kk * 64 + lk * 16) ^ ((prow & 7) << 4))));
    }
#pragma unroll
    for (int i = 0; i < 4; ++i)
#pragma unroll
      for (int j = 0; j < 8; ++j)
        acc[i][j] = __builtin_amdgcn_mfma_f32_16x16x32_bf16(a[i], bb[j], acc[i][j], 0, 0, 0);
  }
  // store y2 pre-BN (no bias) bf16
#pragma unroll
  for (int i = 0; i < 4; ++i) {
    int obch = o0w + i * 16 + lk * 4;
#pragma unroll
    for (int j = 0; j < 8; ++j) {
      int p = p0w + j * 16 + lr;
      u16x4 pk;
      pk[0] = f2b(acc[i][j][0]);
      pk[1] = f2b(acc[i][j][1]);
      pk[2] = f2b(acc[i][j][2]);
      pk[3] = f2b(acc[i][j][3]);
      *(u16x4*)(y2t + (size_t)(bid * 256 + p) * 128 + obch) = pk;
    }
  }
  // BN2 stats partials: sum/sq per channel over this block's 256 points
  float s_[4][4], q_[4][4];
#pragma unroll
  for (int i = 0; i < 4; ++i)
#pragma unroll
    for (int r = 0; r < 4; ++r) {
      float s = 0.f, q = 0.f;
#pragma unroll
      for (int j = 0; j < 8; ++j) {
        float v = acc[i][j][r];
        s += v;
        q = fmaf(v, v, q);
      }
#pragma unroll
      for (int off = 1; off <= 8; off <<= 1) {
        s += __shfl_xor(s, off);
        q += __shfl_xor(q, off);
      }
      s_[i][r] = s;
      q_[i][r] = q;
    }
  __syncthreads();  // safe to reuse XT
  float* Ls = (float*)XT;  // [2 halves][128] sum, then [2][128] sq
  if (lr == 0) {
#pragma unroll
    for (int i = 0; i < 4; ++i)
#pragma unroll
      for (int r = 0; r < 4; ++r) {
        int ch = o0w + i * 16 + lk * 4 + r;
        Ls[(w >> 1) * 128 + ch] = s_[i][r];
        Ls[256 + (w >> 1) * 128 + ch] = q_[i][r];
      }
  }
  __syncthreads();
  if (t < 128) {
    S2P[bid * 256 + t] = Ls[t] + Ls[128 + t];
    S2P[bid * 256 + 128 + t] = Ls[256 + t] + Ls[384 + t];
  }
}

// ---------------- K2: reduce BN2 partials -> SC2 ----------------
__global__ void k_fin2b(const float* __restrict__ S2P, const float* __restrict__ b2,
                        const float* __restrict__ g2, const float* __restrict__ be2,
                        float* __restrict__ SC2) {
  __shared__ float red[2][256];
  int t = threadIdx.x;  // 256
  int o = t & 127, half = t >> 7;
  float s = 0.f, q = 0.f;
  for (int p = half * 128; p < half * 128 + 128; ++p) {
    s += S2P[p * 256 + o];
    q += S2P[p * 256 + 128 + o];
  }
  red[0][t] = s;
  red[1][t] = q;
  __syncthreads();
  if (t < 128) {
    float ss = red[0][t] + red[0][128 + t];
    float qq = red[1][t] + red[1][128 + t];
    float bb = b2[t];
    float sumY = ss + NSf * bb;
    float sumY2 = qq + 2.f * bb * ss + NSf * bb * bb;
    float m = sumY / NSf;
    float v = sumY2 / NSf - m * m;
    float sc = g2[t] * rsqrtf(v + EPS);
    float sh = be2[t] - m * sc;
    SC2[t] = sc;
    SC2[128 + t] = sc * bb + sh;  // fold conv bias into shift
  }
}

// ---- K3: conv3 — W in regs, reg-staged X with BN2+ReLU applied on the fly ---
__global__ __launch_bounds__(256, 2) void k_conv3(const u16* __restrict__ y2t,
                                                  const u16* __restrict__ w3bf,
                                                  const float* __restrict__ SC2,
                                                  float* __restrict__ SUMP,
                                                  float* __restrict__ SQP,
                                                  float* __restrict__ MAXP) {
  __shared__ char XS[32768];  // 2 x 16KB X tiles [64n][128k], swizzled
  int t = threadIdx.x, lane = t & 63;
  int l15 = lane & 15, l4 = lane >> 4;
  int w = __builtin_amdgcn_readfirstlane(t >> 6);
  int D = blockIdx.x;  // 512
  int L = ((D & 7) << 6) | (D >> 3);  // XCD-chunked remap
  int ob = L & 3, b = (L >> 2) & 7, nc = L >> 5;
  int o0 = ob * 256 + w * 64;
  const char* ybase = (const char*)(y2t + ((size_t)(b * 8192 + nc * 512)) * 128);
  // per-thread fixed channel slice for staging
  int colb = (t * 16) & 255, ch0 = colb >> 1;
  float sc_[8], sh_[8];
#pragma unroll
  for (int e = 0; e < 8; ++e) { sc_[e] = SC2[ch0 + e]; sh_[e] = SC2[128 + ch0 + e]; }
  // W fragments: wave-owned o64, loaded once
  bf16x8 af[16];
#pragma unroll
  for (int i = 0; i < 4; ++i)
#pragma unroll
    for (int kk = 0; kk < 4; ++kk)
      af[i * 4 + kk] = *(const bf16x8*)((const char*)w3bf +
          (size_t)(o0 + i * 16 + l15) * 256 + kk * 64 + l4 * 16);
  const f32x4 Z = (f32x4){0.f, 0.f, 0.f, 0.f};
  f32x4 acc[4][4];
  float rmax[4][4], rsum[4][4], rsq[4][4];
#pragma unroll
  for (int i = 0; i < 4; ++i)
#pragma unroll
    for (int j = 0; j < 4; ++j) {
      rmax[i][j] = -1e30f; rsum[i][j] = 0.f; rsq[i][j] = 0.f;
    }
  u16x8 rg[2][4];
#define LD3(tile, sel)                                                                \
  {                                                                                   \
    _Pragma("unroll") for (int q = 0; q < 4; ++q) rg[sel][q] =                        \
        *(const u16x8*)(ybase + (size_t)(tile) * 16384 + q * 4096 + t * 16);          \
  }
#define APPLY3(bufsel, sel)                                                           \
  {                                                                                   \
    _Pragma("unroll") for (int q = 0; q < 4; ++q) {                                   \
      int row = q * 16 + (t >> 4);                                                    \
      u16x8 pk;                                                                       \
      _Pragma("unroll") for (int e = 0; e < 8; ++e) {                                 \
        float f = b2f(rg[sel][q][e]);                                                 \
        pk[e] = f2b(fmaxf(fmaf(sc_[e], f, sh_[e]), 0.f));                             \
      }                                                                               \
      *(u16x8*)(XS + (bufsel) * 16384 + row * 256 + (colb ^ ((row & 7) << 4))) = pk;  \
    }                                                                                 \
  }
  LD3(0, 0);
  LD3(1, 1);
  APPLY3(0, 0);
  __syncthreads();
#pragma unroll
  for (int it = 0; it < 8; ++it) {
    if (it + 2 < 8) LD3(it + 2, it & 1);
#pragma unroll
    for (int kk = 0; kk < 4; ++kk) {
      bf16x8 bf[4];
#pragma unroll
      for (int j = 0; j < 4; ++j) {
        int row = j * 16 + l15;
        bf[j] = *(const bf16x8*)(XS + (it & 1) * 16384 + row * 256 +
                                 ((kk * 64 + (l4 << 4)) ^ ((lane & 7) << 4)));
      }
#pragma unroll
      for (int i = 0; i < 4; ++i)
#pragma unroll
        for (int j = 0; j < 4; ++j)
          acc[i][j] = __builtin_amdgcn_mfma_f32_16x16x32_bf16(
              af[i * 4 + kk], bf[j], (kk == 0) ? Z : acc[i][j], 0, 0, 0);
    }
    if (it + 1 < 8) APPLY3((it + 1) & 1, (it + 1) & 1);
#pragma unroll
    for (int i = 0; i < 4; ++i)
#pragma unroll
      for (int r = 0; r < 4; ++r) {
        float v0 = acc[i][0][r], v1 = acc[i][1][r], v2 = acc[i][2][r], v3 = acc[i][3][r];
        rmax[i][r] = fmaxf(rmax[i][r], fmaxf(fmaxf(v0, v1), fmaxf(v2, v3)));
        rsum[i][r] += (v0 + v1) + (v2 + v3);
        float q01 = fmaf(v0, v0, v1 * v1);
        float q23 = fmaf(v2, v2, v3 * v3);
        rsq[i][r] += q01 + q23;
      }
    __syncthreads();
  }
#pragma unroll
  for (int i = 0; i < 4; ++i)
#pragma unroll
    for (int r = 0; r < 4; ++r) {
      float mx = rmax[i][r], s = rsum[i][r], q = rsq[i][r];
#pragma unroll
      for (int off = 1; off <= 8; off <<= 1) {
        mx = fmaxf(mx, __shfl_xor(mx, off));
        s += __shfl_xor(s, off);
        q += __shfl_xor(q, off);
      }
      if (l15 == 0) {
        int o = o0 + i * 16 + l4 * 4 + r;
        int sl = (nc * 8 + b) * 1024 + o;
        SUMP[sl] = s; SQP[sl] = q; MAXP[sl] = mx;
      }
    }
#undef LD3
#undef APPLY3
}

// ---------------- K4: reduce partials, finalize BN3 + pool ----------------
__global__ void k_pool(const float* __restrict__ SUMP, const float* __restrict__ SQP,
                       const float* __restrict__ MAXP, const float* __restrict__ b3,
                       const float* __restrict__ g3, const float* __restrict__ be3,
                       float* __restrict__ POOL) {
  int idx = blockIdx.x * 256 + threadIdx.x;  // 8192 = b*1024+o
  int b = idx >> 10, o = idx & 1023;
  float s = 0.f, q = 0.f;
  for (int p = 0; p < 128; ++p) {
    s += SUMP[p * 1024 + o];
    q += SQP[p * 1024 + o];
  }
  float mx = -1e30f;
  for (int ncn = 0; ncn < 16; ++ncn) mx = fmaxf(mx, MAXP[(ncn * 8 + b) * 1024 + o]);
  float bb = b3[o];
  float sumY = s + NSf * bb;
  float sumY2 = q + 2.f * bb * s + NSf * bb * bb;
  float m = sumY / NSf;
  float v = sumY2 / NSf - m * m;
  float sc = g3[o] * rsqrtf(v + EPS);
  float sh = be3[o] - m * sc;
  POOL[idx] = fmaxf(fmaf(sc, mx + bb, sh), 0.f);
}

// ---------------- K5/K6: FC + BN(8) + ReLU ----------------
__global__ void k_fc(const float* __restrict__ xin, const float* __restrict__ w,
                     const float* __restrict__ bias, const float* __restrict__ g,
                     const float* __restrict__ be, float* __restrict__ out,
                     int K, int O) {
  int o = blockIdx.x, lane = threadIdx.x;  // 64 threads
  float yb[8] = {0.f, 0.f, 0.f, 0.f, 0.f, 0.f, 0.f, 0.f};
  for (int j = 0; j < K; j += 64) {
    float wv = w[(size_t)o * K + j + lane];
#pragma unroll
    for (int b = 0; b < 8; ++b) yb[b] = fmaf(wv, xin[b * K + j + lane], yb[b]);
  }
#pragma unroll
  for (int b = 0; b < 8; ++b)
    for (int off = 32; off; off >>= 1) yb[b] += __shfl_xor(yb[b], off);
  if (lane == 0) {
    float y[8];
    float m = 0.f;
#pragma unroll
    for (int b = 0; b < 8; ++b) { y[b] = yb[b] + bias[o]; m += y[b]; }
    m *= 0.125f;
    float v = 0.f;
#pragma unroll
    for (int b = 0; b < 8; ++b) { float d = y[b] - m; v = fmaf(d, d, v); }
    v *= 0.125f;
    float sc = g[o] * rsqrtf(v + EPS);
    float sh = be[o] - m * sc;
#pragma unroll
    for (int b = 0; b < 8; ++b) out[b * O + o] = fmaxf(fmaf(sc, y[b], sh), 0.f);
  }
}

// ---- K7: transform (+redundant per-block rot head, +loss via counter) ------
__global__ __launch_bounds__(256) void k_transform(
    const float* __restrict__ src, const float* __restrict__ tgt,
    const float* __restrict__ FC2, const float* __restrict__ wr,
    const float* __restrict__ br, const float* __restrict__ wt,
    const float* __restrict__ bt, float* __restrict__ out,
    float* __restrict__ DIST, unsigned* __restrict__ CNT) {
  int bx = blockIdx.x, t = threadIdx.x;
  int b = bx >> 5;
  int n = ((bx & 31) << 8) + t;
  int w = t >> 6, lane = t & 63;
  __shared__ float RT[12];
  const float* xf = FC2 + b * 256;
#pragma unroll
  for (int jj = 0; jj < 3; ++jj) {
    int j = w * 3 + jj;  // wave-uniform
    float p = 0.f;
#pragma unroll
    for (int i = 0; i < 4; ++i) {
      int kk = i * 64 + lane;
      float wv = (j < 9) ? wr[j * 256 + kk] : wt[(j - 9) * 256 + kk];
      p = fmaf(wv, xf[kk], p);
    }
    for (int off = 32; off; off >>= 1) p += __shfl_xor(p, off);
    if (lane == 0)
      RT[j] = (j < 9) ? (p + br[j] + ((j == 0 || j == 4 || j == 8) ? 1.f : 0.f))
                      : (p + bt[j - 9]);
  }
  __syncthreads();
  float s0 = src[(b * 3 + 0) * 8192 + n];
  float s1 = src[(b * 3 + 1) * 8192 + n];
  float s2 = src[(b * 3 + 2) * 8192 + n];
  float st[3];
#pragma unroll
  for (int c = 0; c < 3; ++c) {
    st[c] = fmaf(s0, RT[c], fmaf(s1, RT[3 + c], fmaf(s2, RT[6 + c], RT[9 + c])));
    out[1 + (b * 3 + c) * 8192 + n] = st[c];
  }
  float tg[3];
#pragma unroll
  for (int i = 0; i < 3; ++i) tg[i] = tgt[(b * 3 + i) * 8192 + n];
  float d[9];
#pragma unroll
  for (int i = 0; i < 3; ++i)
#pragma unroll
    for (int j = 0; j < 3; ++j) {
      float df = st[j] - tg[i];
      d[i * 3 + j] = df * df;
    }
#pragma unroll
  for (int k = 0; k < 9; ++k)
    for (int off = 32; off; off >>= 1) d[k] += __shfl_xor(d[k], off);
  __shared__ float red4[4][9];
  if ((t & 63) == 0) {
#pragma unroll
    for (int k = 0; k < 9; ++k) red4[w][k] = d[k];
  }
  __syncthreads();
  if (t < 9) {
    float s = red4[0][t] + red4[1][t] + red4[2][t] + red4[3][t];
    atomicAdd(&DIST[b * 9 + t], s);
  }
  __syncthreads();
  __shared__ unsigned rank;
  if (t == 0) {
    __threadfence();
    rank = atomicAdd(CNT, 1u);
  }
  __syncthreads();
  if (rank == 255u) {
    __shared__ float Dl[72];
    if (t < 72) Dl[t] = atomicAdd(&DIST[t], 0.f);  // atomic load, L2-coherent
    __syncthreads();
    if (t == 0) {
      float acc = 0.f;
      for (int bb = 0; bb < 8; ++bb) {
        const float* D = Dl + bb * 9;
        for (int j = 0; j < 3; ++j)
          acc += fminf(D[j], fminf(D[3 + j], D[6 + j]));
        for (int i = 0; i < 3; ++i)
          acc += fminf(D[i * 3], fminf(D[i * 3 + 1], D[i * 3 + 2]));
      }
      out[0] = acc / 24.f;
    }
  }
}

extern "C" void kernel_launch(void* const* d_in, const int* in_sizes, int n_in,
                              void* d_out, int out_size, void* d_ws, size_t ws_size,
                              hipStream_t stream) {
  const float* src = (const float*)d_in[0];
  const float* tgt = (const float*)d_in[1];
  const float* w1 = (const float*)d_in[2];
  const float* b1 = (const float*)d_in[3];
  const float* w2 = (const float*)d_in[4];
  const float* b2 = (const float*)d_in[5];
  const float* w3 = (const float*)d_in[6];
  const float* b3 = (const float*)d_in[7];
  const float* fw1 = (const float*)d_in[8];
  const float* fb1 = (const float*)d_in[9];
  const float* fw2 = (const float*)d_in[10];
  const float* fb2 = (const float*)d_in[11];
  const float* wr = (const float*)d_in[12];
  const float* br = (const float*)d_in[13];
  const float* wt = (const float*)d_in[14];
  const float* bt = (const float*)d_in[15];
  const float* g1 = (const float*)d_in[16];
  const float* be1 = (const float*)d_in[17];
  const float* g2 = (const float*)d_in[18];
  const float* be2 = (const float*)d_in[19];
  const float* g3 = (const float*)d_in[20];
  const float* be3 = (const float*)d_in[21];
  const float* g4 = (const float*)d_in[22];
  const float* be4 = (const float*)d_in[23];
  const float* g5 = (const float*)d_in[24];
  const float* be5 = (const float*)d_in[25];
  float* out = (float*)d_out;
  float* ws = (float*)d_ws;
  u16* y2t = (u16*)(ws + WS_Y2T);
  u16* w3bf = (u16*)(ws + WS_W3BF);
  u16* w2bf = (u16*)(ws + WS_W2BF);

  k_prep<<<608, 256, 0, stream>>>(w3, w2, src, w3bf, w2bf, ws + WS_SP, ws + WS_DIST);
  k_conv2<<<256, 256, 0, stream>>>(src, ws + WS_SP, w1, b1, g1, be1, w2bf, y2t,
                                   ws + WS_S2P);
  k_fin2b<<<1, 256, 0, stream>>>(ws + WS_S2P, b2, g2, be2, ws + WS_SC2);
  k_conv3<<<512, 256, 0, stream>>>(y2t, w3bf, ws + WS_SC2, ws + WS_SUMP, ws + WS_SQP,
                                   ws + WS_MAXP);
  k_pool<<<32, 256, 0, stream>>>(ws + WS_SUMP, ws + WS_SQP, ws + WS_MAXP, b3, g3, be3,
                                 ws + WS_POOL);
  k_fc<<<512, 64, 0, stream>>>(ws + WS_POOL, fw1, fb1, g4, be4, ws + WS_FC1, 1024, 512);
  k_fc<<<256, 64, 0, stream>>>(ws + WS_FC1, fw2, fb2, g5, be5, ws + WS_FC2, 512, 256);
  k_transform<<<256, 256, 0, stream>>>(src, tgt, ws + WS_FC2, wr, br, wt, bt, out,
                                       ws + WS_DIST, (unsigned*)(ws + WS_CNT));
}

// Round 8
// 256.806 us; speedup vs baseline: 1.0577x; 1.0577x over previous
//
#include <hip/hip_runtime.h>
#include <hip/hip_bf16.h>

#define EPS 1e-5f
#define NSf 65536.0f

typedef unsigned short u16;
typedef __attribute__((ext_vector_type(8))) unsigned short u16x8;
typedef __attribute__((ext_vector_type(4))) unsigned short u16x4;
typedef __attribute__((ext_vector_type(8))) short bf16x8;
typedef __attribute__((ext_vector_type(4))) float f32x4;

// ---------------- workspace layout (float offsets) ----------------
#define WS_Y2T   0                         // 8,388,608 bf16 (y2 pre-BN)
#define WS_W3BF  4194304                   // 131072 bf16
#define WS_W2BF  4259840                   // 8192 bf16
#define WS_S2P   4263936                   // 256 blocks * 256 f32 (sum128, sq128)
#define WS_SP    4329472                   // 64 * 12 src-moment partials
#define WS_SC2   4330240                   // 256
#define WS_SUMP  4330496                   // 16*8*1024 conv3 sum partials
#define WS_SQP   4461568                   // 16*8*1024 sq partials
#define WS_MAXP  4592640                   // 16*8*1024 max partials
#define WS_POOL  4723712                   // 8192
#define WS_FC1   4731904                   // 4096
#define WS_FC2   4736000                   // 2048
#define WS_DIST  4738048                   // 96 + counter  <- cleared in k_prep
#define WS_CNT   4738144                   // 1
#define WS_END   4738148

__device__ __forceinline__ u16 f2b(float f) {
  unsigned u = __float_as_uint(f);
  u += 0x7FFFu + ((u >> 16) & 1);
  return (u16)(u >> 16);
}
__device__ __forceinline__ float b2f(u16 h) { return __uint_as_float(((unsigned)h) << 16); }

__device__ __forceinline__ void gl16(const void* g, void* l) {
  __builtin_amdgcn_global_load_lds((const __attribute__((address_space(1))) unsigned*)g,
                                   (__attribute__((address_space(3))) unsigned*)l, 16, 0, 0);
}

// ---------------- K0: prep = wcast (544 blocks) + src moments (64) + clears --
__global__ void k_prep(const float* __restrict__ w3, const float* __restrict__ w2,
                       const float* __restrict__ src, u16* __restrict__ w3bf,
                       u16* __restrict__ w2bf, float* __restrict__ SP,
                       float* __restrict__ DIST) {
  int bid = blockIdx.x, t = threadIdx.x;
  if (bid < 544) {
    int id = bid * 256 + t;
    if (id < 131072) w3bf[id] = f2b(w3[id]);
    else w2bf[id - 131072] = f2b(w2[id - 131072]);
    return;
  }
  int sb = bid - 544;  // 0..63
  if (sb == 0 && t < 100) DIST[t] = 0.f;  // DIST[96] + CNT
  float p[9] = {0, 0, 0, 0, 0, 0, 0, 0, 0};
  for (int it = 0; it < 4; ++it) {
    int id = sb * 1024 + it * 256 + t;
    int b = id >> 13, n = id & 8191;
    float s0 = src[(b * 3 + 0) * 8192 + n];
    float s1 = src[(b * 3 + 1) * 8192 + n];
    float s2 = src[(b * 3 + 2) * 8192 + n];
    p[0] += s0; p[1] += s1; p[2] += s2;
    p[3] = fmaf(s0, s0, p[3]); p[4] = fmaf(s0, s1, p[4]); p[5] = fmaf(s0, s2, p[5]);
    p[6] = fmaf(s1, s1, p[6]); p[7] = fmaf(s1, s2, p[7]); p[8] = fmaf(s2, s2, p[8]);
  }
#pragma unroll
  for (int i = 0; i < 9; ++i)
    for (int off = 32; off; off >>= 1) p[i] += __shfl_xor(p[i], off);
  __shared__ float red[4][9];
  int wv = t >> 6;
  if ((t & 63) == 0) {
#pragma unroll
    for (int i = 0; i < 9; ++i) red[wv][i] = p[i];
  }
  __syncthreads();
  if (t < 9) SP[sb * 12 + t] = red[0][t] + red[1][t] + red[2][t] + red[3][t];
}

// ---- K1: conv2 MFMA (fin1 inlined) -> y2 pre-BN bf16 + per-block BN2 partials
__global__ __launch_bounds__(256) void k_conv2(
    const float* __restrict__ src, const float* __restrict__ SP,
    const float* __restrict__ w1, const float* __restrict__ b1,
    const float* __restrict__ g1, const float* __restrict__ be1,
    const u16* __restrict__ w2bf, u16* __restrict__ y2t, float* __restrict__ S2P) {
  __shared__ char WT[16384];  // W2 [128o][64c] bf16 swizzled
  __shared__ char XT[32768];  // x1 [256p][64c] bf16 swizzled
  __shared__ float Msh[9];
  __shared__ float effL[256];
  int t = threadIdx.x, bid = blockIdx.x;
  int lane = t & 63, lr = lane & 15, lk = lane >> 4;
  int w = __builtin_amdgcn_readfirstlane(t >> 6);
#pragma unroll
  for (int i = 0; i < 4; ++i) {
    int s = i * 4096 + t * 16;
    int o = s >> 7, cb = s & 127;
    gl16((const char*)w2bf + ((o << 7) | (cb ^ ((o & 7) << 4))), WT + s);
  }
  int P = bid * 256 + t, b = P >> 13, n = P & 8191;
  float s0 = src[(b * 3 + 0) * 8192 + n];
  float s1 = src[(b * 3 + 1) * 8192 + n];
  float s2 = src[(b * 3 + 2) * 8192 + n];
  // fin1 inline: reduce src moments, compute effective conv1 weights
  if (t < 9) {
    float s = 0.f;
    for (int bb = 0; bb < 64; ++bb) s += SP[bb * 12 + t];
    Msh[t] = s;
  }
  __syncthreads();
  if (t < 64) {
    int c = t;
    float m0 = Msh[0], m1 = Msh[1], m2 = Msh[2];
    float ss00 = Msh[3], ss01 = Msh[4], ss02 = Msh[5], ss11 = Msh[6], ss12 = Msh[7],
          ss22 = Msh[8];
    float a0 = w1[c * 3], a1 = w1[c * 3 + 1], a2 = w1[c * 3 + 2], bb = b1[c];
    float dotS = a0 * m0 + a1 * m1 + a2 * m2;
    float sumY = dotS + NSf * bb;
    float sumY2 = a0 * a0 * ss00 + a1 * a1 * ss11 + a2 * a2 * ss22
                + 2.f * (a0 * a1 * ss01 + a0 * a2 * ss02 + a1 * a2 * ss12)
                + 2.f * bb * dotS + NSf * bb * bb;
    float m = sumY / NSf;
    float v = sumY2 / NSf - m * m;
    float sc = g1[c] * rsqrtf(v + EPS);
    float sh = be1[c] - m * sc;
    effL[c * 3 + 0] = sc * a0;
    effL[c * 3 + 1] = sc * a1;
    effL[c * 3 + 2] = sc * a2;
    effL[192 + c] = sc * bb + sh;
  }
  __syncthreads();
#pragma unroll
  for (int i = 0; i < 8; ++i) {
    u16x8 pk;
#pragma unroll
    for (int e = 0; e < 8; ++e) {
      int c = i * 8 + e;
      pk[e] = f2b(fmaxf(fmaf(effL[c * 3], s0, fmaf(effL[c * 3 + 1], s1,
                        fmaf(effL[c * 3 + 2], s2, effL[192 + c]))), 0.f));
    }
    *(u16x8*)(XT + ((t << 7) | ((i * 16) ^ ((t & 7) << 4)))) = pk;
  }
  __syncthreads();
  int o0w = (w & 1) * 64, p0w = (w >> 1) * 128;
  f32x4 acc[4][8];
#pragma unroll
  for (int i = 0; i < 4; ++i)
#pragma unroll
    for (int j = 0; j < 8; ++j) acc[i][j] = (f32x4){0.f, 0.f, 0.f, 0.f};
#pragma unroll
  for (int kk = 0; kk < 2; ++kk) {
    bf16x8 a[4], bb[8];
#pragma unroll
    for (int i = 0; i < 4; ++i) {
      int row = o0w + i * 16 + lr;
      a[i] = *(const bf16x8*)(WT + ((row << 7) | ((kk * 64 + lk * 16) ^ ((row & 7) << 4))));
    }
#pragma unroll
    for (int j = 0; j < 8; ++j) {
      int prow = p0w + j * 16 + lr;
      bb[j] = *(const bf16x8*)(XT + ((prow << 7) | ((kk * 64 + lk * 16) ^ ((prow & 7) << 4))));
    }
#pragma unroll
    for (int i = 0; i < 4; ++i)
#pragma unroll
      for (int j = 0; j < 8; ++j)
        acc[i][j] = __builtin_amdgcn_mfma_f32_16x16x32_bf16(a[i], bb[j], acc[i][j], 0, 0, 0);
  }
  // store y2 pre-BN (no bias) bf16
#pragma unroll
  for (int i = 0; i < 4; ++i) {
    int obch = o0w + i * 16 + lk * 4;
#pragma unroll
    for (int j = 0; j < 8; ++j) {
      int p = p0w + j * 16 + lr;
      u16x4 pk;
      pk[0] = f2b(acc[i][j][0]);
      pk[1] = f2b(acc[i][j][1]);
      pk[2] = f2b(acc[i][j][2]);
      pk[3] = f2b(acc[i][j][3]);
      *(u16x4*)(y2t + (size_t)(bid * 256 + p) * 128 + obch) = pk;
    }
  }
  // BN2 stats partials: sum/sq per channel over this block's 256 points
  float s_[4][4], q_[4][4];
#pragma unroll
  for (int i = 0; i < 4; ++i)
#pragma unroll
    for (int r = 0; r < 4; ++r) {
      float s = 0.f, q = 0.f;
#pragma unroll
      for (int j = 0; j < 8; ++j) {
        float v = acc[i][j][r];
        s += v;
        q = fmaf(v, v, q);
      }
#pragma unroll
      for (int off = 1; off <= 8; off <<= 1) {
        s += __shfl_xor(s, off);
        q += __shfl_xor(q, off);
      }
      s_[i][r] = s;
      q_[i][r] = q;
    }
  __syncthreads();  // safe to reuse XT
  float* Ls = (float*)XT;  // [2 halves][128] sum, then [2][128] sq
  if (lr == 0) {
#pragma unroll
    for (int i = 0; i < 4; ++i)
#pragma unroll
      for (int r = 0; r < 4; ++r) {
        int ch = o0w + i * 16 + lk * 4 + r;
        Ls[(w >> 1) * 128 + ch] = s_[i][r];
        Ls[256 + (w >> 1) * 128 + ch] = q_[i][r];
      }
  }
  __syncthreads();
  if (t < 128) {
    S2P[bid * 256 + t] = Ls[t] + Ls[128 + t];
    S2P[bid * 256 + 128 + t] = Ls[256 + t] + Ls[384 + t];
  }
}

// ---------------- K2: reduce BN2 partials -> SC2 ----------------
__global__ void k_fin2b(const float* __restrict__ S2P, const float* __restrict__ b2,
                        const float* __restrict__ g2, const float* __restrict__ be2,
                        float* __restrict__ SC2) {
  __shared__ float red[2][256];
  int t = threadIdx.x;  // 256
  int o = t & 127, half = t >> 7;
  float s = 0.f, q = 0.f;
  for (int p = half * 128; p < half * 128 + 128; ++p) {
    s += S2P[p * 256 + o];
    q += S2P[p * 256 + 128 + o];
  }
  red[0][t] = s;
  red[1][t] = q;
  __syncthreads();
  if (t < 128) {
    float ss = red[0][t] + red[0][128 + t];
    float qq = red[1][t] + red[1][128 + t];
    float bb = b2[t];
    float sumY = ss + NSf * bb;
    float sumY2 = qq + 2.f * bb * ss + NSf * bb * bb;
    float m = sumY / NSf;
    float v = sumY2 / NSf - m * m;
    float sc = g2[t] * rsqrtf(v + EPS);
    float sh = be2[t] - m * sc;
    SC2[t] = sc;
    SC2[128 + t] = sc * bb + sh;  // fold conv bias into shift
  }
}

// ---- K3: conv3 — W in regs, reg-staged X (BN2+ReLU on the fly), STATIC regs -
// rule #20 fix: rgA/rgB are separate arrays, only ever indexed by unrolled q.
__global__ __launch_bounds__(256, 2) void k_conv3(const u16* __restrict__ y2t,
                                                  const u16* __restrict__ w3bf,
                                                  const float* __restrict__ SC2,
                                                  float* __restrict__ SUMP,
                                                  float* __restrict__ SQP,
                                                  float* __restrict__ MAXP) {
  __shared__ char XS[32768];  // 2 x 16KB X tiles [64n][128k], swizzled
  int t = threadIdx.x, lane = t & 63;
  int l15 = lane & 15, l4 = lane >> 4;
  int w = __builtin_amdgcn_readfirstlane(t >> 6);  // 4 waves
  int D = blockIdx.x;  // 512
  int L = ((D & 7) << 6) | (D >> 3);  // XCD-chunked remap
  int ob = L & 3, b = (L >> 2) & 7, nc = L >> 5;
  int o0 = ob * 256 + w * 64;
  const char* ybase = (const char*)(y2t + ((size_t)(b * 8192 + nc * 512)) * 128);
  // per-thread fixed channel slice for staging
  int colb = (t * 16) & 255, ch0 = colb >> 1;
  float sc_[8], sh_[8];
#pragma unroll
  for (int e = 0; e < 8; ++e) { sc_[e] = SC2[ch0 + e]; sh_[e] = SC2[128 + ch0 + e]; }
  // W fragments: wave-owned o64, loaded once
  bf16x8 af[16];
#pragma unroll
  for (int i = 0; i < 4; ++i)
#pragma unroll
    for (int kk = 0; kk < 4; ++kk)
      af[i * 4 + kk] = *(const bf16x8*)((const char*)w3bf +
          (size_t)(o0 + i * 16 + l15) * 256 + kk * 64 + l4 * 16);
  const f32x4 Z = (f32x4){0.f, 0.f, 0.f, 0.f};
  f32x4 acc[4][4];
  float rmax[4][4], rsum[4][4], rsq[4][4];
#pragma unroll
  for (int i = 0; i < 4; ++i)
#pragma unroll
    for (int j = 0; j < 4; ++j) {
      rmax[i][j] = -1e30f; rsum[i][j] = 0.f; rsq[i][j] = 0.f;
    }
  u16x8 rgA[4], rgB[4];  // two named buffers, static q-index only
#define LD(rg, tile)                                                                  \
  {                                                                                   \
    _Pragma("unroll") for (int q = 0; q < 4; ++q) rg[q] =                             \
        *(const u16x8*)(ybase + (size_t)(tile) * 16384 + q * 4096 + t * 16);          \
  }
#define APPLY(bufsel, rg)                                                             \
  {                                                                                   \
    _Pragma("unroll") for (int q = 0; q < 4; ++q) {                                   \
      int row = q * 16 + (t >> 4);                                                    \
      u16x8 pk;                                                                       \
      _Pragma("unroll") for (int e = 0; e < 8; ++e) {                                 \
        float f = b2f(rg[q][e]);                                                      \
        pk[e] = f2b(fmaxf(fmaf(sc_[e], f, sh_[e]), 0.f));                             \
      }                                                                               \
      *(u16x8*)(XS + (bufsel) * 16384 + row * 256 + (colb ^ ((row & 7) << 4))) = pk;  \
    }                                                                                 \
  }
#define COMPUTE(bufsel)                                                               \
  {                                                                                   \
    _Pragma("unroll") for (int kk = 0; kk < 4; ++kk) {                                \
      bf16x8 bf[4];                                                                   \
      _Pragma("unroll") for (int j = 0; j < 4; ++j) {                                 \
        int row = j * 16 + l15;                                                       \
        bf[j] = *(const bf16x8*)(XS + (bufsel) * 16384 + row * 256 +                  \
                                 ((kk * 64 + (l4 << 4)) ^ ((lane & 7) << 4)));        \
      }                                                                               \
      _Pragma("unroll") for (int i = 0; i < 4; ++i)                                   \
          _Pragma("unroll") for (int j = 0; j < 4; ++j) acc[i][j] =                   \
          __builtin_amdgcn_mfma_f32_16x16x32_bf16(af[i * 4 + kk], bf[j],              \
                                                  (kk == 0) ? Z : acc[i][j], 0, 0, 0);\
    }                                                                                 \
  }
#define FOLD()                                                                        \
  {                                                                                   \
    _Pragma("unroll") for (int i = 0; i < 4; ++i)                                     \
        _Pragma("unroll") for (int r = 0; r < 4; ++r) {                               \
      float v0 = acc[i][0][r], v1 = acc[i][1][r], v2 = acc[i][2][r], v3 = acc[i][3][r];\
      rmax[i][r] = fmaxf(rmax[i][r], fmaxf(fmaxf(v0, v1), fmaxf(v2, v3)));            \
      rsum[i][r] += (v0 + v1) + (v2 + v3);                                            \
      float q01 = fmaf(v0, v0, v1 * v1);                                              \
      float q23 = fmaf(v2, v2, v3 * v3);                                              \
      rsq[i][r] += q01 + q23;                                                         \
    }                                                                                 \
  }
  LD(rgA, 0); LD(rgB, 1);
  APPLY(0, rgA);
  __syncthreads();
  // it=0
  LD(rgA, 2); COMPUTE(0); APPLY(1, rgB); FOLD(); __syncthreads();
  // it=1
  LD(rgB, 3); COMPUTE(1); APPLY(0, rgA); FOLD(); __syncthreads();
  // it=2
  LD(rgA, 4); COMPUTE(0); APPLY(1, rgB); FOLD(); __syncthreads();
  // it=3
  LD(rgB, 5); COMPUTE(1); APPLY(0, rgA); FOLD(); __syncthreads();
  // it=4
  LD(rgA, 6); COMPUTE(0); APPLY(1, rgB); FOLD(); __syncthreads();
  // it=5
  LD(rgB, 7); COMPUTE(1); APPLY(0, rgA); FOLD(); __syncthreads();
  // it=6
  COMPUTE(0); APPLY(1, rgB); FOLD(); __syncthreads();
  // it=7
  COMPUTE(1); FOLD();
#undef LD
#undef APPLY
#undef COMPUTE
#undef FOLD
  // reduce across the 16 n-lanes, one writer per o (no atomics anywhere)
#pragma unroll
  for (int i = 0; i < 4; ++i)
#pragma unroll
    for (int r = 0; r < 4; ++r) {
      float mx = rmax[i][r], s = rsum[i][r], q = rsq[i][r];
#pragma unroll
      for (int off = 1; off <= 8; off <<= 1) {
        mx = fmaxf(mx, __shfl_xor(mx, off));
        s += __shfl_xor(s, off);
        q += __shfl_xor(q, off);
      }
      if (l15 == 0) {
        int o = o0 + i * 16 + l4 * 4 + r;
        int sl = (nc * 8 + b) * 1024 + o;
        SUMP[sl] = s; SQP[sl] = q; MAXP[sl] = mx;
      }
    }
}

// ---------------- K4: reduce partials, finalize BN3 + pool ----------------
__global__ void k_pool(const float* __restrict__ SUMP, const float* __restrict__ SQP,
                       const float* __restrict__ MAXP, const float* __restrict__ b3,
                       const float* __restrict__ g3, const float* __restrict__ be3,
                       float* __restrict__ POOL) {
  int idx = blockIdx.x * 256 + threadIdx.x;  // 8192 = b*1024+o
  int b = idx >> 10, o = idx & 1023;
  float s = 0.f, q = 0.f;
  for (int p = 0; p < 128; ++p) {
    s += SUMP[p * 1024 + o];
    q += SQP[p * 1024 + o];
  }
  float mx = -1e30f;
  for (int ncn = 0; ncn < 16; ++ncn) mx = fmaxf(mx, MAXP[(ncn * 8 + b) * 1024 + o]);
  float bb = b3[o];
  float sumY = s + NSf * bb;
  float sumY2 = q + 2.f * bb * s + NSf * bb * bb;
  float m = sumY / NSf;
  float v = sumY2 / NSf - m * m;
  float sc = g3[o] * rsqrtf(v + EPS);
  float sh = be3[o] - m * sc;
  POOL[idx] = fmaxf(fmaf(sc, mx + bb, sh), 0.f);
}

// ---------------- K5/K6: FC + BN(8) + ReLU ----------------
__global__ void k_fc(const float* __restrict__ xin, const float* __restrict__ w,
                     const float* __restrict__ bias, const float* __restrict__ g,
                     const float* __restrict__ be, float* __restrict__ out,
                     int K, int O) {
  int o = blockIdx.x, lane = threadIdx.x;  // 64 threads
  float yb[8] = {0.f, 0.f, 0.f, 0.f, 0.f, 0.f, 0.f, 0.f};
  for (int j = 0; j < K; j += 64) {
    float wv = w[(size_t)o * K + j + lane];
#pragma unroll
    for (int b = 0; b < 8; ++b) yb[b] = fmaf(wv, xin[b * K + j + lane], yb[b]);
  }
#pragma unroll
  for (int b = 0; b < 8; ++b)
    for (int off = 32; off; off >>= 1) yb[b] += __shfl_xor(yb[b], off);
  if (lane == 0) {
    float y[8];
    float m = 0.f;
#pragma unroll
    for (int b = 0; b < 8; ++b) { y[b] = yb[b] + bias[o]; m += y[b]; }
    m *= 0.125f;
    float v = 0.f;
#pragma unroll
    for (int b = 0; b < 8; ++b) { float d = y[b] - m; v = fmaf(d, d, v); }
    v *= 0.125f;
    float sc = g[o] * rsqrtf(v + EPS);
    float sh = be[o] - m * sc;
#pragma unroll
    for (int b = 0; b < 8; ++b) out[b * O + o] = fmaxf(fmaf(sc, y[b], sh), 0.f);
  }
}

// ---- K7: transform (+redundant per-block rot head, +loss via counter) ------
__global__ __launch_bounds__(256) void k_transform(
    const float* __restrict__ src, const float* __restrict__ tgt,
    const float* __restrict__ FC2, const float* __restrict__ wr,
    const float* __restrict__ br, const float* __restrict__ wt,
    const float* __restrict__ bt, float* __restrict__ out,
    float* __restrict__ DIST, unsigned* __restrict__ CNT) {
  int bx = blockIdx.x, t = threadIdx.x;
  int b = bx >> 5;
  int n = ((bx & 31) << 8) + t;
  int w = t >> 6, lane = t & 63;
  __shared__ float RT[12];
  const float* xf = FC2 + b * 256;
#pragma unroll
  for (int jj = 0; jj < 3; ++jj) {
    int j = w * 3 + jj;  // wave-uniform
    float p = 0.f;
#pragma unroll
    for (int i = 0; i < 4; ++i) {
      int kk = i * 64 + lane;
      float wv = (j < 9) ? wr[j * 256 + kk] : wt[(j - 9) * 256 + kk];
      p = fmaf(wv, xf[kk], p);
    }
    for (int off = 32; off; off >>= 1) p += __shfl_xor(p, off);
    if (lane == 0)
      RT[j] = (j < 9) ? (p + br[j] + ((j == 0 || j == 4 || j == 8) ? 1.f : 0.f))
                      : (p + bt[j - 9]);
  }
  __syncthreads();
  float s0 = src[(b * 3 + 0) * 8192 + n];
  float s1 = src[(b * 3 + 1) * 8192 + n];
  float s2 = src[(b * 3 + 2) * 8192 + n];
  float st[3];
#pragma unroll
  for (int c = 0; c < 3; ++c) {
    st[c] = fmaf(s0, RT[c], fmaf(s1, RT[3 + c], fmaf(s2, RT[6 + c], RT[9 + c])));
    out[1 + (b * 3 + c) * 8192 + n] = st[c];
  }
  float tg[3];
#pragma unroll
  for (int i = 0; i < 3; ++i) tg[i] = tgt[(b * 3 + i) * 8192 + n];
  float d[9];
#pragma unroll
  for (int i = 0; i < 3; ++i)
#pragma unroll
    for (int j = 0; j < 3; ++j) {
      float df = st[j] - tg[i];
      d[i * 3 + j] = df * df;
    }
#pragma unroll
  for (int k = 0; k < 9; ++k)
    for (int off = 32; off; off >>= 1) d[k] += __shfl_xor(d[k], off);
  __shared__ float red4[4][9];
  if ((t & 63) == 0) {
#pragma unroll
    for (int k = 0; k < 9; ++k) red4[w][k] = d[k];
  }
  __syncthreads();
  if (t < 9) {
    float s = red4[0][t] + red4[1][t] + red4[2][t] + red4[3][t];
    atomicAdd(&DIST[b * 9 + t], s);
  }
  __syncthreads();
  __shared__ unsigned rank;
  if (t == 0) {
    __threadfence();
    rank = atomicAdd(CNT, 1u);
  }
  __syncthreads();
  if (rank == 255u) {
    __shared__ float Dl[72];
    if (t < 72) Dl[t] = atomicAdd(&DIST[t], 0.f);  // atomic load, L2-coherent
    __syncthreads();
    if (t == 0) {
      float acc = 0.f;
      for (int bb = 0; bb < 8; ++bb) {
        const float* D = Dl + bb * 9;
        for (int j = 0; j < 3; ++j)
          acc += fminf(D[j], fminf(D[3 + j], D[6 + j]));
        for (int i = 0; i < 3; ++i)
          acc += fminf(D[i * 3], fminf(D[i * 3 + 1], D[i * 3 + 2]));
      }
      out[0] = acc / 24.f;
    }
  }
}

extern "C" void kernel_launch(void* const* d_in, const int* in_sizes, int n_in,
                              void* d_out, int out_size, void* d_ws, size_t ws_size,
                              hipStream_t stream) {
  const float* src = (const float*)d_in[0];
  const float* tgt = (const float*)d_in[1];
  const float* w1 = (const float*)d_in[2];
  const float* b1 = (const float*)d_in[3];
  const float* w2 = (const float*)d_in[4];
  const float* b2 = (const float*)d_in[5];
  const float* w3 = (const float*)d_in[6];
  const float* b3 = (const float*)d_in[7];
  const float* fw1 = (const float*)d_in[8];
  const float* fb1 = (const float*)d_in[9];
  const float* fw2 = (const float*)d_in[10];
  const float* fb2 = (const float*)d_in[11];
  const float* wr = (const float*)d_in[12];
  const float* br = (const float*)d_in[13];
  const float* wt = (const float*)d_in[14];
  const float* bt = (const float*)d_in[15];
  const float* g1 = (const float*)d_in[16];
  const float* be1 = (const float*)d_in[17];
  const float* g2 = (const float*)d_in[18];
  const float* be2 = (const float*)d_in[19];
  const float* g3 = (const float*)d_in[20];
  const float* be3 = (const float*)d_in[21];
  const float* g4 = (const float*)d_in[22];
  const float* be4 = (const float*)d_in[23];
  const float* g5 = (const float*)d_in[24];
  const float* be5 = (const float*)d_in[25];
  float* out = (float*)d_out;
  float* ws = (float*)d_ws;
  u16* y2t = (u16*)(ws + WS_Y2T);
  u16* w3bf = (u16*)(ws + WS_W3BF);
  u16* w2bf = (u16*)(ws + WS_W2BF);

  k_prep<<<608, 256, 0, stream>>>(w3, w2, src, w3bf, w2bf, ws + WS_SP, ws + WS_DIST);
  k_conv2<<<256, 256, 0, stream>>>(src, ws + WS_SP, w1, b1, g1, be1, w2bf, y2t,
                                   ws + WS_S2P);
  k_fin2b<<<1, 256, 0, stream>>>(ws + WS_S2P, b2, g2, be2, ws + WS_SC2);
  k_conv3<<<512, 256, 0, stream>>>(y2t, w3bf, ws + WS_SC2, ws + WS_SUMP, ws + WS_SQP,
                                   ws + WS_MAXP);
  k_pool<<<32, 256, 0, stream>>>(ws + WS_SUMP, ws + WS_SQP, ws + WS_MAXP, b3, g3, be3,
                                 ws + WS_POOL);
  k_fc<<<512, 64, 0, stream>>>(ws + WS_POOL, fw1, fb1, g4, be4, ws + WS_FC1, 1024, 512);
  k_fc<<<256, 64, 0, stream>>>(ws + WS_FC1, fw2, fb2, g5, be5, ws + WS_FC2, 512, 256);
  k_transform<<<256, 256, 0, stream>>>(src, tgt, ws + WS_FC2, wr, br, wt, bt, out,
                                       ws + WS_DIST, (unsigned*)(ws + WS_CNT));
}

// Round 9
// 124.103 us; speedup vs baseline: 2.1886x; 2.0693x over previous
//
#include <hip/hip_runtime.h>
#include <hip/hip_bf16.h>

#define EPS 1e-5f
#define NSf 65536.0f

typedef unsigned short u16;
typedef __attribute__((ext_vector_type(8))) unsigned short u16x8;
typedef __attribute__((ext_vector_type(4))) unsigned short u16x4;
typedef __attribute__((ext_vector_type(8))) short bf16x8;
typedef __attribute__((ext_vector_type(4))) float f32x4;

// ---------------- workspace layout (float offsets) ----------------
#define WS_Y2T   0                         // 8,388,608 bf16 (y2 pre-BN -> x2 after bnapply)
#define WS_W3BF  4194304                   // 131072 bf16
#define WS_W2BF  4259840                   // 8192 bf16
#define WS_S2P   4263936                   // 256 blocks * 256 f32 (sum128, sq128)
#define WS_SP    4329472                   // 64 * 12 src-moment partials
#define WS_SC2   4330240                   // 256
#define WS_SUMP  4330496                   // 16*8*1024 conv3 sum partials
#define WS_SQP   4461568                   // 16*8*1024 sq partials
#define WS_MAXP  4592640                   // 16*8*1024 max partials
#define WS_POOL  4723712                   // 8192
#define WS_FC1   4731904                   // 4096
#define WS_FC2   4736000                   // 2048
#define WS_DIST  4738048                   // 96 + counter  <- cleared in k_prep
#define WS_CNT   4738144                   // 1
#define WS_END   4738148

__device__ __forceinline__ u16 f2b(float f) {
  unsigned u = __float_as_uint(f);
  u += 0x7FFFu + ((u >> 16) & 1);
  return (u16)(u >> 16);
}
__device__ __forceinline__ float b2f(u16 h) { return __uint_as_float(((unsigned)h) << 16); }

__device__ __forceinline__ void gl16(const void* g, void* l) {
  __builtin_amdgcn_global_load_lds((const __attribute__((address_space(1))) unsigned*)g,
                                   (__attribute__((address_space(3))) unsigned*)l, 16, 0, 0);
}

// ---------------- K0: prep = wcast (544 blocks) + src moments (64) + clears --
__global__ void k_prep(const float* __restrict__ w3, const float* __restrict__ w2,
                       const float* __restrict__ src, u16* __restrict__ w3bf,
                       u16* __restrict__ w2bf, float* __restrict__ SP,
                       float* __restrict__ DIST) {
  int bid = blockIdx.x, t = threadIdx.x;
  if (bid < 544) {
    int id = bid * 256 + t;
    if (id < 131072) w3bf[id] = f2b(w3[id]);
    else w2bf[id - 131072] = f2b(w2[id - 131072]);
    return;
  }
  int sb = bid - 544;  // 0..63
  if (sb == 0 && t < 100) DIST[t] = 0.f;  // DIST[96] + CNT
  float p[9] = {0, 0, 0, 0, 0, 0, 0, 0, 0};
  for (int it = 0; it < 4; ++it) {
    int id = sb * 1024 + it * 256 + t;
    int b = id >> 13, n = id & 8191;
    float s0 = src[(b * 3 + 0) * 8192 + n];
    float s1 = src[(b * 3 + 1) * 8192 + n];
    float s2 = src[(b * 3 + 2) * 8192 + n];
    p[0] += s0; p[1] += s1; p[2] += s2;
    p[3] = fmaf(s0, s0, p[3]); p[4] = fmaf(s0, s1, p[4]); p[5] = fmaf(s0, s2, p[5]);
    p[6] = fmaf(s1, s1, p[6]); p[7] = fmaf(s1, s2, p[7]); p[8] = fmaf(s2, s2, p[8]);
  }
#pragma unroll
  for (int i = 0; i < 9; ++i)
    for (int off = 32; off; off >>= 1) p[i] += __shfl_xor(p[i], off);
  __shared__ float red[4][9];
  int wv = t >> 6;
  if ((t & 63) == 0) {
#pragma unroll
    for (int i = 0; i < 9; ++i) red[wv][i] = p[i];
  }
  __syncthreads();
  if (t < 9) SP[sb * 12 + t] = red[0][t] + red[1][t] + red[2][t] + red[3][t];
}

// ---- K1: conv2 MFMA (fin1 inlined) -> y2 pre-BN bf16 + per-block BN2 partials
__global__ __launch_bounds__(256) void k_conv2(
    const float* __restrict__ src, const float* __restrict__ SP,
    const float* __restrict__ w1, const float* __restrict__ b1,
    const float* __restrict__ g1, const float* __restrict__ be1,
    const u16* __restrict__ w2bf, u16* __restrict__ y2t, float* __restrict__ S2P) {
  __shared__ char WT[16384];  // W2 [128o][64c] bf16 swizzled
  __shared__ char XT[32768];  // x1 [256p][64c] bf16 swizzled
  __shared__ float Msh[9];
  __shared__ float effL[256];
  int t = threadIdx.x, bid = blockIdx.x;
  int lane = t & 63, lr = lane & 15, lk = lane >> 4;
  int w = __builtin_amdgcn_readfirstlane(t >> 6);
#pragma unroll
  for (int i = 0; i < 4; ++i) {
    int s = i * 4096 + t * 16;
    int o = s >> 7, cb = s & 127;
    gl16((const char*)w2bf + ((o << 7) | (cb ^ ((o & 7) << 4))), WT + s);
  }
  int P = bid * 256 + t, b = P >> 13, n = P & 8191;
  float s0 = src[(b * 3 + 0) * 8192 + n];
  float s1 = src[(b * 3 + 1) * 8192 + n];
  float s2 = src[(b * 3 + 2) * 8192 + n];
  // fin1 inline: reduce src moments, compute effective conv1 weights
  if (t < 9) {
    float s = 0.f;
    for (int bb = 0; bb < 64; ++bb) s += SP[bb * 12 + t];
    Msh[t] = s;
  }
  __syncthreads();
  if (t < 64) {
    int c = t;
    float m0 = Msh[0], m1 = Msh[1], m2 = Msh[2];
    float ss00 = Msh[3], ss01 = Msh[4], ss02 = Msh[5], ss11 = Msh[6], ss12 = Msh[7],
          ss22 = Msh[8];
    float a0 = w1[c * 3], a1 = w1[c * 3 + 1], a2 = w1[c * 3 + 2], bb = b1[c];
    float dotS = a0 * m0 + a1 * m1 + a2 * m2;
    float sumY = dotS + NSf * bb;
    float sumY2 = a0 * a0 * ss00 + a1 * a1 * ss11 + a2 * a2 * ss22
                + 2.f * (a0 * a1 * ss01 + a0 * a2 * ss02 + a1 * a2 * ss12)
                + 2.f * bb * dotS + NSf * bb * bb;
    float m = sumY / NSf;
    float v = sumY2 / NSf - m * m;
    float sc = g1[c] * rsqrtf(v + EPS);
    float sh = be1[c] - m * sc;
    effL[c * 3 + 0] = sc * a0;
    effL[c * 3 + 1] = sc * a1;
    effL[c * 3 + 2] = sc * a2;
    effL[192 + c] = sc * bb + sh;
  }
  __syncthreads();
#pragma unroll
  for (int i = 0; i < 8; ++i) {
    u16x8 pk;
#pragma unroll
    for (int e = 0; e < 8; ++e) {
      int c = i * 8 + e;
      pk[e] = f2b(fmaxf(fmaf(effL[c * 3], s0, fmaf(effL[c * 3 + 1], s1,
                        fmaf(effL[c * 3 + 2], s2, effL[192 + c]))), 0.f));
    }
    *(u16x8*)(XT + ((t << 7) | ((i * 16) ^ ((t & 7) << 4)))) = pk;
  }
  __syncthreads();
  int o0w = (w & 1) * 64, p0w = (w >> 1) * 128;
  f32x4 acc[4][8];
#pragma unroll
  for (int i = 0; i < 4; ++i)
#pragma unroll
    for (int j = 0; j < 8; ++j) acc[i][j] = (f32x4){0.f, 0.f, 0.f, 0.f};
#pragma unroll
  for (int kk = 0; kk < 2; ++kk) {
    bf16x8 a[4], bb[8];
#pragma unroll
    for (int i = 0; i < 4; ++i) {
      int row = o0w + i * 16 + lr;
      a[i] = *(const bf16x8*)(WT + ((row << 7) | ((kk * 64 + lk * 16) ^ ((row & 7) << 4))));
    }
#pragma unroll
    for (int j = 0; j < 8; ++j) {
      int prow = p0w + j * 16 + lr;
      bb[j] = *(const bf16x8*)(XT + ((prow << 7) | ((kk * 64 + lk * 16) ^ ((prow & 7) << 4))));
    }
#pragma unroll
    for (int i = 0; i < 4; ++i)
#pragma unroll
      for (int j = 0; j < 8; ++j)
        acc[i][j] = __builtin_amdgcn_mfma_f32_16x16x32_bf16(a[i], bb[j], acc[i][j], 0, 0, 0);
  }
  // store y2 pre-BN (no bias) bf16
#pragma unroll
  for (int i = 0; i < 4; ++i) {
    int obch = o0w + i * 16 + lk * 4;
#pragma unroll
    for (int j = 0; j < 8; ++j) {
      int p = p0w + j * 16 + lr;
      u16x4 pk;
      pk[0] = f2b(acc[i][j][0]);
      pk[1] = f2b(acc[i][j][1]);
      pk[2] = f2b(acc[i][j][2]);
      pk[3] = f2b(acc[i][j][3]);
      *(u16x4*)(y2t + (size_t)(bid * 256 + p) * 128 + obch) = pk;
    }
  }
  // BN2 stats partials: sum/sq per channel over this block's 256 points
  float s_[4][4], q_[4][4];
#pragma unroll
  for (int i = 0; i < 4; ++i)
#pragma unroll
    for (int r = 0; r < 4; ++r) {
      float s = 0.f, q = 0.f;
#pragma unroll
      for (int j = 0; j < 8; ++j) {
        float v = acc[i][j][r];
        s += v;
        q = fmaf(v, v, q);
      }
#pragma unroll
      for (int off = 1; off <= 8; off <<= 1) {
        s += __shfl_xor(s, off);
        q += __shfl_xor(q, off);
      }
      s_[i][r] = s;
      q_[i][r] = q;
    }
  __syncthreads();  // safe to reuse XT
  float* Ls = (float*)XT;  // [2 halves][128] sum, then [2][128] sq
  if (lr == 0) {
#pragma unroll
    for (int i = 0; i < 4; ++i)
#pragma unroll
      for (int r = 0; r < 4; ++r) {
        int ch = o0w + i * 16 + lk * 4 + r;
        Ls[(w >> 1) * 128 + ch] = s_[i][r];
        Ls[256 + (w >> 1) * 128 + ch] = q_[i][r];
      }
  }
  __syncthreads();
  if (t < 128) {
    S2P[bid * 256 + t] = Ls[t] + Ls[128 + t];
    S2P[bid * 256 + 128 + t] = Ls[256 + t] + Ls[384 + t];
  }
}

// ---------------- K2: reduce BN2 partials -> SC2 ----------------
__global__ void k_fin2b(const float* __restrict__ S2P, const float* __restrict__ b2,
                        const float* __restrict__ g2, const float* __restrict__ be2,
                        float* __restrict__ SC2) {
  __shared__ float red[2][256];
  int t = threadIdx.x;  // 256
  int o = t & 127, half = t >> 7;
  float s = 0.f, q = 0.f;
  for (int p = half * 128; p < half * 128 + 128; ++p) {
    s += S2P[p * 256 + o];
    q += S2P[p * 256 + 128 + o];
  }
  red[0][t] = s;
  red[1][t] = q;
  __syncthreads();
  if (t < 128) {
    float ss = red[0][t] + red[0][128 + t];
    float qq = red[1][t] + red[1][128 + t];
    float bb = b2[t];
    float sumY = ss + NSf * bb;
    float sumY2 = qq + 2.f * bb * ss + NSf * bb * bb;
    float m = sumY / NSf;
    float v = sumY2 / NSf - m * m;
    float sc = g2[t] * rsqrtf(v + EPS);
    float sh = be2[t] - m * sc;
    SC2[t] = sc;
    SC2[128 + t] = sc * bb + sh;  // fold conv bias into shift
  }
}

// ---------------- K3: bnapply — y2 -> x2 = relu(sc*y2+sh) in place -----------
__global__ __launch_bounds__(256) void k_bnapply(u16* __restrict__ y2t,
                                                 const float* __restrict__ SC2) {
  int t = threadIdx.x, bid = blockIdx.x;  // 1024 blocks
  int base = bid * 256 + t;               // u16x8 chunk id stride 262144
  int ch0 = (base & 15) * 8;
  float sc0 = SC2[ch0 + 0], sc1 = SC2[ch0 + 1], sc2 = SC2[ch0 + 2], sc3 = SC2[ch0 + 3];
  float sc4 = SC2[ch0 + 4], sc5 = SC2[ch0 + 5], sc6 = SC2[ch0 + 6], sc7 = SC2[ch0 + 7];
  float sh0 = SC2[128 + ch0 + 0], sh1 = SC2[128 + ch0 + 1], sh2 = SC2[128 + ch0 + 2];
  float sh3 = SC2[128 + ch0 + 3], sh4 = SC2[128 + ch0 + 4], sh5 = SC2[128 + ch0 + 5];
  float sh6 = SC2[128 + ch0 + 6], sh7 = SC2[128 + ch0 + 7];
#pragma unroll
  for (int i = 0; i < 4; ++i) {
    u16x8* p = (u16x8*)(y2t + (size_t)(i * 262144 + base) * 8);
    u16x8 v = *p;
    u16x8 r;
    r[0] = f2b(fmaxf(fmaf(sc0, b2f(v[0]), sh0), 0.f));
    r[1] = f2b(fmaxf(fmaf(sc1, b2f(v[1]), sh1), 0.f));
    r[2] = f2b(fmaxf(fmaf(sc2, b2f(v[2]), sh2), 0.f));
    r[3] = f2b(fmaxf(fmaf(sc3, b2f(v[3]), sh3), 0.f));
    r[4] = f2b(fmaxf(fmaf(sc4, b2f(v[4]), sh4), 0.f));
    r[5] = f2b(fmaxf(fmaf(sc5, b2f(v[5]), sh5), 0.f));
    r[6] = f2b(fmaxf(fmaf(sc6, b2f(v[6]), sh6), 0.f));
    r[7] = f2b(fmaxf(fmaf(sc7, b2f(v[7]), sh7), 0.f));
    *p = r;
  }
}

// ---- K4: conv3 — W in regs, X streamed via global_load_lds (round-4 proven) -
__device__ __forceinline__ void stage_x(const u16* __restrict__ xit, char* dst, int t) {
#pragma unroll
  for (int q = 0; q < 4; ++q) {
    int s = q * 4096 + t * 16;
    int row = s >> 8, colb = s & 255;
    gl16((const char*)xit + row * 256 + (colb ^ ((row & 7) << 4)), dst + s);
  }
}

__global__ __launch_bounds__(256, 2) void k_conv3(const u16* __restrict__ x2t,
                                                  const u16* __restrict__ w3bf,
                                                  float* __restrict__ SUMP,
                                                  float* __restrict__ SQP,
                                                  float* __restrict__ MAXP) {
  __shared__ char XS[32768];  // 2 x 16KB X tiles [64n][128k], swizzled
  int t = threadIdx.x, lane = t & 63;
  int l15 = lane & 15, l4 = lane >> 4;
  int w = __builtin_amdgcn_readfirstlane(t >> 6);
  int D = blockIdx.x;                      // 512
  int L = ((D & 7) << 6) | (D >> 3);       // XCD-chunked remap
  int ob = L & 3, b = (L >> 2) & 7, nc = L >> 5;
  int o0 = ob * 256 + w * 64;
  const u16* xbase = x2t + ((size_t)(b * 8192 + nc * 512)) * 128;
  bf16x8 af[16];
#pragma unroll
  for (int i = 0; i < 4; ++i)
#pragma unroll
    for (int kk = 0; kk < 4; ++kk)
      af[i * 4 + kk] = *(const bf16x8*)((const char*)w3bf +
          (size_t)(o0 + i * 16 + l15) * 256 + kk * 64 + l4 * 16);
  const f32x4 Z = (f32x4){0.f, 0.f, 0.f, 0.f};
  f32x4 acc[4][4];
  float rmax[4][4], rsum[4][4], rsq[4][4];
#pragma unroll
  for (int i = 0; i < 4; ++i)
#pragma unroll
    for (int j = 0; j < 4; ++j) {
      rmax[i][j] = -1e30f; rsum[i][j] = 0.f; rsq[i][j] = 0.f;
    }
  stage_x(xbase, XS, t);
  __syncthreads();
  for (int it = 0; it < 8; ++it) {
    if (it < 7) stage_x(xbase + (size_t)(it + 1) * 8192, XS + ((it + 1) & 1) * 16384, t);
    const char* xb = XS + (it & 1) * 16384;
#pragma unroll
    for (int kk = 0; kk < 4; ++kk) {
      bf16x8 bf[4];
#pragma unroll
      for (int j = 0; j < 4; ++j) {
        int row = j * 16 + l15;
        bf[j] = *(const bf16x8*)(xb + row * 256 + ((kk * 64 + (l4 << 4)) ^ ((lane & 7) << 4)));
      }
#pragma unroll
      for (int i = 0; i < 4; ++i)
#pragma unroll
        for (int j = 0; j < 4; ++j)
          acc[i][j] = __builtin_amdgcn_mfma_f32_16x16x32_bf16(
              af[i * 4 + kk], bf[j], (kk == 0) ? Z : acc[i][j], 0, 0, 0);
    }
#pragma unroll
    for (int i = 0; i < 4; ++i)
#pragma unroll
      for (int r = 0; r < 4; ++r) {
        float v0 = acc[i][0][r], v1 = acc[i][1][r], v2 = acc[i][2][r], v3 = acc[i][3][r];
        rmax[i][r] = fmaxf(rmax[i][r], fmaxf(fmaxf(v0, v1), fmaxf(v2, v3)));
        rsum[i][r] += (v0 + v1) + (v2 + v3);
        float q01 = fmaf(v0, v0, v1 * v1);
        float q23 = fmaf(v2, v2, v3 * v3);
        rsq[i][r] += q01 + q23;
      }
    __syncthreads();
  }
#pragma unroll
  for (int i = 0; i < 4; ++i)
#pragma unroll
    for (int r = 0; r < 4; ++r) {
      float mx = rmax[i][r], s = rsum[i][r], q = rsq[i][r];
#pragma unroll
      for (int off = 1; off <= 8; off <<= 1) {
        mx = fmaxf(mx, __shfl_xor(mx, off));
        s += __shfl_xor(s, off);
        q += __shfl_xor(q, off);
      }
      if (l15 == 0) {
        int o = o0 + i * 16 + l4 * 4 + r;
        int sl = (nc * 8 + b) * 1024 + o;
        SUMP[sl] = s; SQP[sl] = q; MAXP[sl] = mx;
      }
    }
}

// ---------------- K5: reduce partials, finalize BN3 + pool ----------------
__global__ void k_pool(const float* __restrict__ SUMP, const float* __restrict__ SQP,
                       const float* __restrict__ MAXP, const float* __restrict__ b3,
                       const float* __restrict__ g3, const float* __restrict__ be3,
                       float* __restrict__ POOL) {
  int idx = blockIdx.x * 256 + threadIdx.x;  // 8192 = b*1024+o
  int b = idx >> 10, o = idx & 1023;
  float s = 0.f, q = 0.f;
  for (int p = 0; p < 128; ++p) {
    s += SUMP[p * 1024 + o];
    q += SQP[p * 1024 + o];
  }
  float mx = -1e30f;
  for (int ncn = 0; ncn < 16; ++ncn) mx = fmaxf(mx, MAXP[(ncn * 8 + b) * 1024 + o]);
  float bb = b3[o];
  float sumY = s + NSf * bb;
  float sumY2 = q + 2.f * bb * s + NSf * bb * bb;
  float m = sumY / NSf;
  float v = sumY2 / NSf - m * m;
  float sc = g3[o] * rsqrtf(v + EPS);
  float sh = be3[o] - m * sc;
  POOL[idx] = fmaxf(fmaf(sc, mx + bb, sh), 0.f);
}

// ---------------- K6/K7: FC + BN(8) + ReLU ----------------
__global__ void k_fc(const float* __restrict__ xin, const float* __restrict__ w,
                     const float* __restrict__ bias, const float* __restrict__ g,
                     const float* __restrict__ be, float* __restrict__ out,
                     int K, int O) {
  int o = blockIdx.x, lane = threadIdx.x;  // 64 threads
  float yb[8] = {0.f, 0.f, 0.f, 0.f, 0.f, 0.f, 0.f, 0.f};
  for (int j = 0; j < K; j += 64) {
    float wv = w[(size_t)o * K + j + lane];
#pragma unroll
    for (int b = 0; b < 8; ++b) yb[b] = fmaf(wv, xin[b * K + j + lane], yb[b]);
  }
#pragma unroll
  for (int b = 0; b < 8; ++b)
    for (int off = 32; off; off >>= 1) yb[b] += __shfl_xor(yb[b], off);
  if (lane == 0) {
    float y[8];
    float m = 0.f;
#pragma unroll
    for (int b = 0; b < 8; ++b) { y[b] = yb[b] + bias[o]; m += y[b]; }
    m *= 0.125f;
    float v = 0.f;
#pragma unroll
    for (int b = 0; b < 8; ++b) { float d = y[b] - m; v = fmaf(d, d, v); }
    v *= 0.125f;
    float sc = g[o] * rsqrtf(v + EPS);
    float sh = be[o] - m * sc;
#pragma unroll
    for (int b = 0; b < 8; ++b) out[b * O + o] = fmaxf(fmaf(sc, y[b], sh), 0.f);
  }
}

// ---- K8: transform (+redundant per-block rot head, +loss via counter) ------
__global__ __launch_bounds__(256) void k_transform(
    const float* __restrict__ src, const float* __restrict__ tgt,
    const float* __restrict__ FC2, const float* __restrict__ wr,
    const float* __restrict__ br, const float* __restrict__ wt,
    const float* __restrict__ bt, float* __restrict__ out,
    float* __restrict__ DIST, unsigned* __restrict__ CNT) {
  int bx = blockIdx.x, t = threadIdx.x;
  int b = bx >> 5;
  int n = ((bx & 31) << 8) + t;
  int w = t >> 6, lane = t & 63;
  __shared__ float RT[12];
  const float* xf = FC2 + b * 256;
#pragma unroll
  for (int jj = 0; jj < 3; ++jj) {
    int j = w * 3 + jj;  // wave-uniform
    float p = 0.f;
#pragma unroll
    for (int i = 0; i < 4; ++i) {
      int kk = i * 64 + lane;
      float wv = (j < 9) ? wr[j * 256 + kk] : wt[(j - 9) * 256 + kk];
      p = fmaf(wv, xf[kk], p);
    }
    for (int off = 32; off; off >>= 1) p += __shfl_xor(p, off);
    if (lane == 0)
      RT[j] = (j < 9) ? (p + br[j] + ((j == 0 || j == 4 || j == 8) ? 1.f : 0.f))
                      : (p + bt[j - 9]);
  }
  __syncthreads();
  float s0 = src[(b * 3 + 0) * 8192 + n];
  float s1 = src[(b * 3 + 1) * 8192 + n];
  float s2 = src[(b * 3 + 2) * 8192 + n];
  float st[3];
#pragma unroll
  for (int c = 0; c < 3; ++c) {
    st[c] = fmaf(s0, RT[c], fmaf(s1, RT[3 + c], fmaf(s2, RT[6 + c], RT[9 + c])));
    out[1 + (b * 3 + c) * 8192 + n] = st[c];
  }
  float tg[3];
#pragma unroll
  for (int i = 0; i < 3; ++i) tg[i] = tgt[(b * 3 + i) * 8192 + n];
  float d[9];
#pragma unroll
  for (int i = 0; i < 3; ++i)
#pragma unroll
    for (int j = 0; j < 3; ++j) {
      float df = st[j] - tg[i];
      d[i * 3 + j] = df * df;
    }
#pragma unroll
  for (int k = 0; k < 9; ++k)
    for (int off = 32; off; off >>= 1) d[k] += __shfl_xor(d[k], off);
  __shared__ float red4[4][9];
  if ((t & 63) == 0) {
#pragma unroll
    for (int k = 0; k < 9; ++k) red4[w][k] = d[k];
  }
  __syncthreads();
  if (t < 9) {
    float s = red4[0][t] + red4[1][t] + red4[2][t] + red4[3][t];
    atomicAdd(&DIST[b * 9 + t], s);
  }
  __syncthreads();
  __shared__ unsigned rank;
  if (t == 0) {
    __threadfence();
    rank = atomicAdd(CNT, 1u);
  }
  __syncthreads();
  if (rank == 255u) {
    __shared__ float Dl[72];
    if (t < 72) Dl[t] = atomicAdd(&DIST[t], 0.f);  // atomic load, L2-coherent
    __syncthreads();
    if (t == 0) {
      float acc = 0.f;
      for (int bb = 0; bb < 8; ++bb) {
        const float* D = Dl + bb * 9;
        for (int j = 0; j < 3; ++j)
          acc += fminf(D[j], fminf(D[3 + j], D[6 + j]));
        for (int i = 0; i < 3; ++i)
          acc += fminf(D[i * 3], fminf(D[i * 3 + 1], D[i * 3 + 2]));
      }
      out[0] = acc / 24.f;
    }
  }
}

extern "C" void kernel_launch(void* const* d_in, const int* in_sizes, int n_in,
                              void* d_out, int out_size, void* d_ws, size_t ws_size,
                              hipStream_t stream) {
  const float* src = (const float*)d_in[0];
  const float* tgt = (const float*)d_in[1];
  const float* w1 = (const float*)d_in[2];
  const float* b1 = (const float*)d_in[3];
  const float* w2 = (const float*)d_in[4];
  const float* b2 = (const float*)d_in[5];
  const float* w3 = (const float*)d_in[6];
  const float* b3 = (const float*)d_in[7];
  const float* fw1 = (const float*)d_in[8];
  const float* fb1 = (const float*)d_in[9];
  const float* fw2 = (const float*)d_in[10];
  const float* fb2 = (const float*)d_in[11];
  const float* wr = (const float*)d_in[12];
  const float* br = (const float*)d_in[13];
  const float* wt = (const float*)d_in[14];
  const float* bt = (const float*)d_in[15];
  const float* g1 = (const float*)d_in[16];
  const float* be1 = (const float*)d_in[17];
  const float* g2 = (const float*)d_in[18];
  const float* be2 = (const float*)d_in[19];
  const float* g3 = (const float*)d_in[20];
  const float* be3 = (const float*)d_in[21];
  const float* g4 = (const float*)d_in[22];
  const float* be4 = (const float*)d_in[23];
  const float* g5 = (const float*)d_in[24];
  const float* be5 = (const float*)d_in[25];
  float* out = (float*)d_out;
  float* ws = (float*)d_ws;
  u16* y2t = (u16*)(ws + WS_Y2T);
  u16* w3bf = (u16*)(ws + WS_W3BF);
  u16* w2bf = (u16*)(ws + WS_W2BF);

  k_prep<<<608, 256, 0, stream>>>(w3, w2, src, w3bf, w2bf, ws + WS_SP, ws + WS_DIST);
  k_conv2<<<256, 256, 0, stream>>>(src, ws + WS_SP, w1, b1, g1, be1, w2bf, y2t,
                                   ws + WS_S2P);
  k_fin2b<<<1, 256, 0, stream>>>(ws + WS_S2P, b2, g2, be2, ws + WS_SC2);
  k_bnapply<<<1024, 256, 0, stream>>>(y2t, ws + WS_SC2);
  k_conv3<<<512, 256, 0, stream>>>(y2t, w3bf, ws + WS_SUMP, ws + WS_SQP, ws + WS_MAXP);
  k_pool<<<32, 256, 0, stream>>>(ws + WS_SUMP, ws + WS_SQP, ws + WS_MAXP, b3, g3, be3,
                                 ws + WS_POOL);
  k_fc<<<512, 64, 0, stream>>>(ws + WS_POOL, fw1, fb1, g4, be4, ws + WS_FC1, 1024, 512);
  k_fc<<<256, 64, 0, stream>>>(ws + WS_FC1, fw2, fb2, g5, be5, ws + WS_FC2, 512, 256);
  k_transform<<<256, 256, 0, stream>>>(src, tgt, ws + WS_FC2, wr, br, wt, bt, out,
                                       ws + WS_DIST, (unsigned*)(ws + WS_CNT));
}

// Round 10
// 93.472 us; speedup vs baseline: 2.9058x; 1.3277x over previous
//
#include <hip/hip_runtime.h>
#include <hip/hip_bf16.h>

#define EPS 1e-5f
#define NSf 65536.0f

typedef unsigned short u16;
typedef __attribute__((ext_vector_type(8))) unsigned short u16x8;
typedef __attribute__((ext_vector_type(4))) unsigned short u16x4;
typedef __attribute__((ext_vector_type(8))) short bf16x8;
typedef __attribute__((ext_vector_type(4))) float f32x4;

// ---------------- workspace layout (float offsets) ----------------
#define WS_Y2T   0                         // 8,388,608 bf16 (y2 pre-BN)
#define WS_W3BF  4194304                   // 131072 bf16
#define WS_W2BF  4259840                   // 8192 bf16
#define WS_SP    4263936                   // 64 * 12 src-moment partials
#define WS_SC2   4264704                   // 256
#define WS_S2S   4264960                   // 16 slots * 256 (sum128, sq128) <- cleared
#define WS_DIST  4269056                   // 96                             <- cleared
#define WS_CNT2  4269152                   // 1                              <- cleared
#define WS_CNT   4269153                   // 1                              <- cleared
#define WS_CLRN  4194                      // clear span from WS_S2S
#define WS_SUMP  4269184                   // 16*8*1024 conv3 sum partials
#define WS_SQP   4400256                   // 16*8*1024 sq partials
#define WS_MAXP  4531328                   // 16*8*1024 max partials
#define WS_POOL  4662400                   // 8192
#define WS_FC1   4670592                   // 4096
#define WS_FC2   4674688                   // 2048
#define WS_END   4676736

__device__ __forceinline__ u16 f2b(float f) {
  unsigned u = __float_as_uint(f);
  u += 0x7FFFu + ((u >> 16) & 1);
  return (u16)(u >> 16);
}
__device__ __forceinline__ float b2f(u16 h) { return __uint_as_float(((unsigned)h) << 16); }

__device__ __forceinline__ void gl16(const void* g, void* l) {
  __builtin_amdgcn_global_load_lds((const __attribute__((address_space(1))) unsigned*)g,
                                   (__attribute__((address_space(3))) unsigned*)l, 16, 0, 0);
}

// ---------------- K0: prep = wcast (544 blocks) + src moments (64) + clears --
__global__ void k_prep(const float* __restrict__ w3, const float* __restrict__ w2,
                       const float* __restrict__ src, u16* __restrict__ w3bf,
                       u16* __restrict__ w2bf, float* __restrict__ SP,
                       float* __restrict__ CLR) {
  int bid = blockIdx.x, t = threadIdx.x;
  if (bid < 544) {
    int id = bid * 256 + t;
    if (id < 131072) w3bf[id] = f2b(w3[id]);
    else w2bf[id - 131072] = f2b(w2[id - 131072]);
    return;
  }
  int sb = bid - 544;  // 0..63
  int ci = sb * 256 + t;
  if (ci < WS_CLRN) ((unsigned*)CLR)[ci] = 0u;
  float p[9] = {0, 0, 0, 0, 0, 0, 0, 0, 0};
  for (int it = 0; it < 4; ++it) {
    int id = sb * 1024 + it * 256 + t;
    int b = id >> 13, n = id & 8191;
    float s0 = src[(b * 3 + 0) * 8192 + n];
    float s1 = src[(b * 3 + 1) * 8192 + n];
    float s2 = src[(b * 3 + 2) * 8192 + n];
    p[0] += s0; p[1] += s1; p[2] += s2;
    p[3] = fmaf(s0, s0, p[3]); p[4] = fmaf(s0, s1, p[4]); p[5] = fmaf(s0, s2, p[5]);
    p[6] = fmaf(s1, s1, p[6]); p[7] = fmaf(s1, s2, p[7]); p[8] = fmaf(s2, s2, p[8]);
  }
#pragma unroll
  for (int i = 0; i < 9; ++i)
    for (int off = 32; off; off >>= 1) p[i] += __shfl_xor(p[i], off);
  __shared__ float red[4][9];
  int wv = t >> 6;
  if ((t & 63) == 0) {
#pragma unroll
    for (int i = 0; i < 9; ++i) red[wv][i] = p[i];
  }
  __syncthreads();
  if (t < 9) SP[sb * 12 + t] = red[0][t] + red[1][t] + red[2][t] + red[3][t];
}

// ---- K1: conv2 MFMA (fin1 inlined) -> y2 pre-BN bf16; slotted BN2 stats
//      atomics; 256th block (completion counter) computes SC2.
__global__ __launch_bounds__(256) void k_conv2(
    const float* __restrict__ src, const float* __restrict__ SP,
    const float* __restrict__ w1, const float* __restrict__ b1,
    const float* __restrict__ g1, const float* __restrict__ be1,
    const float* __restrict__ b2, const float* __restrict__ g2,
    const float* __restrict__ be2, const u16* __restrict__ w2bf,
    u16* __restrict__ y2t, float* __restrict__ S2S, float* __restrict__ SC2,
    unsigned* __restrict__ CNT2) {
  __shared__ char WT[16384];  // W2 [128o][64c] bf16 swizzled
  __shared__ char XT[32768];  // x1 [256p][64c] bf16 swizzled
  __shared__ float Msh[9];
  __shared__ float effL[256];
  int t = threadIdx.x, bid = blockIdx.x;
  int lane = t & 63, lr = lane & 15, lk = lane >> 4;
  int w = __builtin_amdgcn_readfirstlane(t >> 6);
#pragma unroll
  for (int i = 0; i < 4; ++i) {
    int s = i * 4096 + t * 16;
    int o = s >> 7, cb = s & 127;
    gl16((const char*)w2bf + ((o << 7) | (cb ^ ((o & 7) << 4))), WT + s);
  }
  int P = bid * 256 + t, b = P >> 13, n = P & 8191;
  float s0 = src[(b * 3 + 0) * 8192 + n];
  float s1 = src[(b * 3 + 1) * 8192 + n];
  float s2 = src[(b * 3 + 2) * 8192 + n];
  // fin1 inline
  if (t < 9) {
    float s = 0.f;
    for (int bb = 0; bb < 64; ++bb) s += SP[bb * 12 + t];
    Msh[t] = s;
  }
  __syncthreads();
  if (t < 64) {
    int c = t;
    float m0 = Msh[0], m1 = Msh[1], m2 = Msh[2];
    float ss00 = Msh[3], ss01 = Msh[4], ss02 = Msh[5], ss11 = Msh[6], ss12 = Msh[7],
          ss22 = Msh[8];
    float a0 = w1[c * 3], a1 = w1[c * 3 + 1], a2 = w1[c * 3 + 2], bb = b1[c];
    float dotS = a0 * m0 + a1 * m1 + a2 * m2;
    float sumY = dotS + NSf * bb;
    float sumY2 = a0 * a0 * ss00 + a1 * a1 * ss11 + a2 * a2 * ss22
                + 2.f * (a0 * a1 * ss01 + a0 * a2 * ss02 + a1 * a2 * ss12)
                + 2.f * bb * dotS + NSf * bb * bb;
    float m = sumY / NSf;
    float v = sumY2 / NSf - m * m;
    float sc = g1[c] * rsqrtf(v + EPS);
    float sh = be1[c] - m * sc;
    effL[c * 3 + 0] = sc * a0;
    effL[c * 3 + 1] = sc * a1;
    effL[c * 3 + 2] = sc * a2;
    effL[192 + c] = sc * bb + sh;
  }
  __syncthreads();
#pragma unroll
  for (int i = 0; i < 8; ++i) {
    u16x8 pk;
#pragma unroll
    for (int e = 0; e < 8; ++e) {
      int c = i * 8 + e;
      pk[e] = f2b(fmaxf(fmaf(effL[c * 3], s0, fmaf(effL[c * 3 + 1], s1,
                        fmaf(effL[c * 3 + 2], s2, effL[192 + c]))), 0.f));
    }
    *(u16x8*)(XT + ((t << 7) | ((i * 16) ^ ((t & 7) << 4)))) = pk;
  }
  __syncthreads();
  int o0w = (w & 1) * 64, p0w = (w >> 1) * 128;
  f32x4 acc[4][8];
#pragma unroll
  for (int i = 0; i < 4; ++i)
#pragma unroll
    for (int j = 0; j < 8; ++j) acc[i][j] = (f32x4){0.f, 0.f, 0.f, 0.f};
#pragma unroll
  for (int kk = 0; kk < 2; ++kk) {
    bf16x8 a[4], bb[8];
#pragma unroll
    for (int i = 0; i < 4; ++i) {
      int row = o0w + i * 16 + lr;
      a[i] = *(const bf16x8*)(WT + ((row << 7) | ((kk * 64 + lk * 16) ^ ((row & 7) << 4))));
    }
#pragma unroll
    for (int j = 0; j < 8; ++j) {
      int prow = p0w + j * 16 + lr;
      bb[j] = *(const bf16x8*)(XT + ((prow << 7) | ((kk * 64 + lk * 16) ^ ((prow & 7) << 4))));
    }
#pragma unroll
    for (int i = 0; i < 4; ++i)
#pragma unroll
      for (int j = 0; j < 8; ++j)
        acc[i][j] = __builtin_amdgcn_mfma_f32_16x16x32_bf16(a[i], bb[j], acc[i][j], 0, 0, 0);
  }
  // store y2 pre-BN (no bias) bf16
#pragma unroll
  for (int i = 0; i < 4; ++i) {
    int obch = o0w + i * 16 + lk * 4;
#pragma unroll
    for (int j = 0; j < 8; ++j) {
      int p = p0w + j * 16 + lr;
      u16x4 pk;
      pk[0] = f2b(acc[i][j][0]);
      pk[1] = f2b(acc[i][j][1]);
      pk[2] = f2b(acc[i][j][2]);
      pk[3] = f2b(acc[i][j][3]);
      *(u16x4*)(y2t + (size_t)(bid * 256 + p) * 128 + obch) = pk;
    }
  }
  // BN2 stats: per-channel sum/sq over this block's 256 points -> slotted atomics
  int slot = (bid & 15) * 256;
#pragma unroll
  for (int i = 0; i < 4; ++i)
#pragma unroll
    for (int r = 0; r < 4; ++r) {
      float s = 0.f, q = 0.f;
#pragma unroll
      for (int j = 0; j < 8; ++j) {
        float v = acc[i][j][r];
        s += v;
        q = fmaf(v, v, q);
      }
#pragma unroll
      for (int off = 1; off <= 8; off <<= 1) {
        s += __shfl_xor(s, off);
        q += __shfl_xor(q, off);
      }
      if (lr == 0) {
        int ch = o0w + i * 16 + lk * 4 + r;
        atomicAdd(&S2S[slot + ch], s);
        atomicAdd(&S2S[slot + 128 + ch], q);
      }
    }
  // completion counter: last block computes SC2
  __syncthreads();  // drains this block's atomics (vmcnt) before fence+count
  __shared__ unsigned rank2;
  if (t == 0) {
    __threadfence();
    rank2 = atomicAdd(CNT2, 1u);
  }
  __syncthreads();
  if (rank2 == 255u && t < 128) {
    float s = 0.f, q = 0.f;
#pragma unroll
    for (int sl = 0; sl < 16; ++sl) {
      s += atomicAdd(&S2S[sl * 256 + t], 0.f);        // atomic load, device-coherent
      q += atomicAdd(&S2S[sl * 256 + 128 + t], 0.f);
    }
    float bb = b2[t];
    float sumY = s + NSf * bb;
    float sumY2 = q + 2.f * bb * s + NSf * bb * bb;
    float m = sumY / NSf;
    float v = sumY2 / NSf - m * m;
    float sc = g2[t] * rsqrtf(v + EPS);
    float sh = be2[t] - m * sc;
    SC2[t] = sc;
    SC2[128 + t] = sc * bb + sh;  // fold conv bias into shift
  }
}

// ---- K2: conv3 — W in regs, raw y2 streamed via global_load_lds, BN2+ReLU
//      applied by in-LDS RMW (channel set per thread is swizzle-invariant).
__device__ __forceinline__ void stage_x(const u16* __restrict__ xit, char* dst, int t) {
#pragma unroll
  for (int q = 0; q < 4; ++q) {
    int s = q * 4096 + t * 16;
    int row = s >> 8, colb = s & 255;
    gl16((const char*)xit + row * 256 + (colb ^ ((row & 7) << 4)), dst + s);
  }
}

__global__ __launch_bounds__(256, 2) void k_conv3(const u16* __restrict__ y2t,
                                                  const u16* __restrict__ w3bf,
                                                  const float* __restrict__ SC2,
                                                  float* __restrict__ SUMP,
                                                  float* __restrict__ SQP,
                                                  float* __restrict__ MAXP) {
  __shared__ char XS[32768];  // 2 x 16KB tiles [64n][128k], swizzled
  int t = threadIdx.x, lane = t & 63;
  int l15 = lane & 15, l4 = lane >> 4;
  int w = __builtin_amdgcn_readfirstlane(t >> 6);
  int D = blockIdx.x;                      // 512
  int L = ((D & 7) << 6) | (D >> 3);       // XCD-chunked remap
  int ob = L & 3, b = (L >> 2) & 7, nc = L >> 5;
  int o0 = ob * 256 + w * 64;
  const u16* xbase = y2t + ((size_t)(b * 8192 + nc * 512)) * 128;
  // fixed channel slice per thread: row&7 == (t>>4)&7 for every staged chunk
  int ch0 = (((t & 15) * 16) ^ (((t >> 4) & 7) << 4)) >> 1;
  float sc_[8], sh_[8];
#pragma unroll
  for (int e = 0; e < 8; ++e) { sc_[e] = SC2[ch0 + e]; sh_[e] = SC2[128 + ch0 + e]; }
  bf16x8 af[16];
#pragma unroll
  for (int i = 0; i < 4; ++i)
#pragma unroll
    for (int kk = 0; kk < 4; ++kk)
      af[i * 4 + kk] = *(const bf16x8*)((const char*)w3bf +
          (size_t)(o0 + i * 16 + l15) * 256 + kk * 64 + l4 * 16);
  const f32x4 Z = (f32x4){0.f, 0.f, 0.f, 0.f};
  f32x4 acc[4][4];
  float rmax[4][4], rsum[4][4], rsq[4][4];
#pragma unroll
  for (int i = 0; i < 4; ++i)
#pragma unroll
    for (int j = 0; j < 4; ++j) {
      rmax[i][j] = -1e30f; rsum[i][j] = 0.f; rsq[i][j] = 0.f;
    }
#define RMW(bufsel)                                                                   \
  {                                                                                   \
    _Pragma("unroll") for (int q = 0; q < 4; ++q) {                                   \
      char* pp = XS + (bufsel) * 16384 + q * 4096 + t * 16;                           \
      u16x8 v = *(u16x8*)pp;                                                          \
      u16x8 rr;                                                                       \
      _Pragma("unroll") for (int e = 0; e < 8; ++e)                                   \
          rr[e] = f2b(fmaxf(fmaf(sc_[e], b2f(v[e]), sh_[e]), 0.f));                   \
      *(u16x8*)pp = rr;                                                               \
    }                                                                                 \
  }
  stage_x(xbase, XS, t);
  __syncthreads();  // vmcnt drain: tile 0 staged
  RMW(0);
  __syncthreads();
  for (int it = 0; it < 8; ++it) {
    if (it < 7) stage_x(xbase + (size_t)(it + 1) * 8192, XS + ((it + 1) & 1) * 16384, t);
    const char* xb = XS + (it & 1) * 16384;
#pragma unroll
    for (int kk = 0; kk < 4; ++kk) {
      bf16x8 bf[4];
#pragma unroll
      for (int j = 0; j < 4; ++j) {
        int row = j * 16 + l15;
        bf[j] = *(const bf16x8*)(xb + row * 256 + ((kk * 64 + (l4 << 4)) ^ ((lane & 7) << 4)));
      }
#pragma unroll
      for (int i = 0; i < 4; ++i)
#pragma unroll
        for (int j = 0; j < 4; ++j)
          acc[i][j] = __builtin_amdgcn_mfma_f32_16x16x32_bf16(
              af[i * 4 + kk], bf[j], (kk == 0) ? Z : acc[i][j], 0, 0, 0);
    }
#pragma unroll
    for (int i = 0; i < 4; ++i)
#pragma unroll
      for (int r = 0; r < 4; ++r) {
        float v0 = acc[i][0][r], v1 = acc[i][1][r], v2 = acc[i][2][r], v3 = acc[i][3][r];
        rmax[i][r] = fmaxf(rmax[i][r], fmaxf(fmaxf(v0, v1), fmaxf(v2, v3)));
        rsum[i][r] += (v0 + v1) + (v2 + v3);
        float q01 = fmaf(v0, v0, v1 * v1);
        float q23 = fmaf(v2, v2, v3 * v3);
        rsq[i][r] += q01 + q23;
      }
    __syncthreads();  // all reads of buf[it&1] done; stage(it+1) landed (vmcnt)
    if (it < 7) {
      RMW((it + 1) & 1);
      __syncthreads();
    }
  }
#undef RMW
#pragma unroll
  for (int i = 0; i < 4; ++i)
#pragma unroll
    for (int r = 0; r < 4; ++r) {
      float mx = rmax[i][r], s = rsum[i][r], q = rsq[i][r];
#pragma unroll
      for (int off = 1; off <= 8; off <<= 1) {
        mx = fmaxf(mx, __shfl_xor(mx, off));
        s += __shfl_xor(s, off);
        q += __shfl_xor(q, off);
      }
      if (l15 == 0) {
        int o = o0 + i * 16 + l4 * 4 + r;
        int sl = (nc * 8 + b) * 1024 + o;
        SUMP[sl] = s; SQP[sl] = q; MAXP[sl] = mx;
      }
    }
}

// ---------------- K3: reduce partials, finalize BN3 + pool ----------------
__global__ void k_pool(const float* __restrict__ SUMP, const float* __restrict__ SQP,
                       const float* __restrict__ MAXP, const float* __restrict__ b3,
                       const float* __restrict__ g3, const float* __restrict__ be3,
                       float* __restrict__ POOL) {
  int idx = blockIdx.x * 256 + threadIdx.x;  // 8192 = b*1024+o
  int b = idx >> 10, o = idx & 1023;
  float s = 0.f, q = 0.f;
  for (int p = 0; p < 128; ++p) {
    s += SUMP[p * 1024 + o];
    q += SQP[p * 1024 + o];
  }
  float mx = -1e30f;
  for (int ncn = 0; ncn < 16; ++ncn) mx = fmaxf(mx, MAXP[(ncn * 8 + b) * 1024 + o]);
  float bb = b3[o];
  float sumY = s + NSf * bb;
  float sumY2 = q + 2.f * bb * s + NSf * bb * bb;
  float m = sumY / NSf;
  float v = sumY2 / NSf - m * m;
  float sc = g3[o] * rsqrtf(v + EPS);
  float sh = be3[o] - m * sc;
  POOL[idx] = fmaxf(fmaf(sc, mx + bb, sh), 0.f);
}

// ---------------- K4/K5: FC + BN(8) + ReLU ----------------
__global__ void k_fc(const float* __restrict__ xin, const float* __restrict__ w,
                     const float* __restrict__ bias, const float* __restrict__ g,
                     const float* __restrict__ be, float* __restrict__ out,
                     int K, int O) {
  int o = blockIdx.x, lane = threadIdx.x;  // 64 threads
  float yb[8] = {0.f, 0.f, 0.f, 0.f, 0.f, 0.f, 0.f, 0.f};
  for (int j = 0; j < K; j += 64) {
    float wv = w[(size_t)o * K + j + lane];
#pragma unroll
    for (int b = 0; b < 8; ++b) yb[b] = fmaf(wv, xin[b * K + j + lane], yb[b]);
  }
#pragma unroll
  for (int b = 0; b < 8; ++b)
    for (int off = 32; off; off >>= 1) yb[b] += __shfl_xor(yb[b], off);
  if (lane == 0) {
    float y[8];
    float m = 0.f;
#pragma unroll
    for (int b = 0; b < 8; ++b) { y[b] = yb[b] + bias[o]; m += y[b]; }
    m *= 0.125f;
    float v = 0.f;
#pragma unroll
    for (int b = 0; b < 8; ++b) { float d = y[b] - m; v = fmaf(d, d, v); }
    v *= 0.125f;
    float sc = g[o] * rsqrtf(v + EPS);
    float sh = be[o] - m * sc;
#pragma unroll
    for (int b = 0; b < 8; ++b) out[b * O + o] = fmaxf(fmaf(sc, y[b], sh), 0.f);
  }
}

// ---- K6: transform (+redundant per-block rot head, +loss via counter) ------
__global__ __launch_bounds__(256) void k_transform(
    const float* __restrict__ src, const float* __restrict__ tgt,
    const float* __restrict__ FC2, const float* __restrict__ wr,
    const float* __restrict__ br, const float* __restrict__ wt,
    const float* __restrict__ bt, float* __restrict__ out,
    float* __restrict__ DIST, unsigned* __restrict__ CNT) {
  int bx = blockIdx.x, t = threadIdx.x;
  int b = bx >> 5;
  int n = ((bx & 31) << 8) + t;
  int w = t >> 6, lane = t & 63;
  __shared__ float RT[12];
  const float* xf = FC2 + b * 256;
#pragma unroll
  for (int jj = 0; jj < 3; ++jj) {
    int j = w * 3 + jj;  // wave-uniform
    float p = 0.f;
#pragma unroll
    for (int i = 0; i < 4; ++i) {
      int kk = i * 64 + lane;
      float wv = (j < 9) ? wr[j * 256 + kk] : wt[(j - 9) * 256 + kk];
      p = fmaf(wv, xf[kk], p);
    }
    for (int off = 32; off; off >>= 1) p += __shfl_xor(p, off);
    if (lane == 0)
      RT[j] = (j < 9) ? (p + br[j] + ((j == 0 || j == 4 || j == 8) ? 1.f : 0.f))
                      : (p + bt[j - 9]);
  }
  __syncthreads();
  float s0 = src[(b * 3 + 0) * 8192 + n];
  float s1 = src[(b * 3 + 1) * 8192 + n];
  float s2 = src[(b * 3 + 2) * 8192 + n];
  float st[3];
#pragma unroll
  for (int c = 0; c < 3; ++c) {
    st[c] = fmaf(s0, RT[c], fmaf(s1, RT[3 + c], fmaf(s2, RT[6 + c], RT[9 + c])));
    out[1 + (b * 3 + c) * 8192 + n] = st[c];
  }
  float tg[3];
#pragma unroll
  for (int i = 0; i < 3; ++i) tg[i] = tgt[(b * 3 + i) * 8192 + n];
  float d[9];
#pragma unroll
  for (int i = 0; i < 3; ++i)
#pragma unroll
    for (int j = 0; j < 3; ++j) {
      float df = st[j] - tg[i];
      d[i * 3 + j] = df * df;
    }
#pragma unroll
  for (int k = 0; k < 9; ++k)
    for (int off = 32; off; off >>= 1) d[k] += __shfl_xor(d[k], off);
  __shared__ float red4[4][9];
  if ((t & 63) == 0) {
#pragma unroll
    for (int k = 0; k < 9; ++k) red4[w][k] = d[k];
  }
  __syncthreads();
  if (t < 9) {
    float s = red4[0][t] + red4[1][t] + red4[2][t] + red4[3][t];
    atomicAdd(&DIST[b * 9 + t], s);
  }
  __syncthreads();
  __shared__ unsigned rank;
  if (t == 0) {
    __threadfence();
    rank = atomicAdd(CNT, 1u);
  }
  __syncthreads();
  if (rank == 255u) {
    __shared__ float Dl[72];
    if (t < 72) Dl[t] = atomicAdd(&DIST[t], 0.f);  // atomic load, device-coherent
    __syncthreads();
    if (t == 0) {
      float acc = 0.f;
      for (int bb = 0; bb < 8; ++bb) {
        const float* D = Dl + bb * 9;
        for (int j = 0; j < 3; ++j)
          acc += fminf(D[j], fminf(D[3 + j], D[6 + j]));
        for (int i = 0; i < 3; ++i)
          acc += fminf(D[i * 3], fminf(D[i * 3 + 1], D[i * 3 + 2]));
      }
      out[0] = acc / 24.f;
    }
  }
}

extern "C" void kernel_launch(void* const* d_in, const int* in_sizes, int n_in,
                              void* d_out, int out_size, void* d_ws, size_t ws_size,
                              hipStream_t stream) {
  const float* src = (const float*)d_in[0];
  const float* tgt = (const float*)d_in[1];
  const float* w1 = (const float*)d_in[2];
  const float* b1 = (const float*)d_in[3];
  const float* w2 = (const float*)d_in[4];
  const float* b2 = (const float*)d_in[5];
  const float* w3 = (const float*)d_in[6];
  const float* b3 = (const float*)d_in[7];
  const float* fw1 = (const float*)d_in[8];
  const float* fb1 = (const float*)d_in[9];
  const float* fw2 = (const float*)d_in[10];
  const float* fb2 = (const float*)d_in[11];
  const float* wr = (const float*)d_in[12];
  const float* br = (const float*)d_in[13];
  const float* wt = (const float*)d_in[14];
  const float* bt = (const float*)d_in[15];
  const float* g1 = (const float*)d_in[16];
  const float* be1 = (const float*)d_in[17];
  const float* g2 = (const float*)d_in[18];
  const float* be2 = (const float*)d_in[19];
  const float* g3 = (const float*)d_in[20];
  const float* be3 = (const float*)d_in[21];
  const float* g4 = (const float*)d_in[22];
  const float* be4 = (const float*)d_in[23];
  const float* g5 = (const float*)d_in[24];
  const float* be5 = (const float*)d_in[25];
  float* out = (float*)d_out;
  float* ws = (float*)d_ws;
  u16* y2t = (u16*)(ws + WS_Y2T);
  u16* w3bf = (u16*)(ws + WS_W3BF);
  u16* w2bf = (u16*)(ws + WS_W2BF);

  k_prep<<<608, 256, 0, stream>>>(w3, w2, src, w3bf, w2bf, ws + WS_SP, ws + WS_S2S);
  k_conv2<<<256, 256, 0, stream>>>(src, ws + WS_SP, w1, b1, g1, be1, b2, g2, be2,
                                   w2bf, y2t, ws + WS_S2S, ws + WS_SC2,
                                   (unsigned*)(ws + WS_CNT2));
  k_conv3<<<512, 256, 0, stream>>>(y2t, w3bf, ws + WS_SC2, ws + WS_SUMP, ws + WS_SQP,
                                   ws + WS_MAXP);
  k_pool<<<32, 256, 0, stream>>>(ws + WS_SUMP, ws + WS_SQP, ws + WS_MAXP, b3, g3, be3,
                                 ws + WS_POOL);
  k_fc<<<512, 64, 0, stream>>>(ws + WS_POOL, fw1, fb1, g4, be4, ws + WS_FC1, 1024, 512);
  k_fc<<<256, 64, 0, stream>>>(ws + WS_FC1, fw2, fb2, g5, be5, ws + WS_FC2, 512, 256);
  k_transform<<<256, 256, 0, stream>>>(src, tgt, ws + WS_FC2, wr, br, wt, bt, out,
                                       ws + WS_DIST, (unsigned*)(ws + WS_CNT));
}